// Round 4
// baseline (202.320 us; speedup 1.0000x reference)
//
#include <hip/hip_runtime.h>
#include <hip/hip_bf16.h>

typedef __attribute__((ext_vector_type(8))) short bf16x8;
typedef __attribute__((ext_vector_type(4))) float f32x4;
typedef __attribute__((ext_vector_type(16))) float f32x16;

#define B_DIM  2
#define S_DIM  2048
#define D_DIM  1024
#define H_DIM  16
#define HD_DIM 64

__device__ __forceinline__ float bf2f(ushort u) {
    union { unsigned int ui; float f; } c; c.ui = ((unsigned int)u) << 16; return c.f;
}
__device__ __forceinline__ ushort f2bf(float f) {
    __hip_bfloat16 h = __float2bfloat16(f);
    return *reinterpret_cast<ushort*>(&h);
}

// Async global->LDS DMA, 16 B per lane. LDS dest = wave-uniform base + lane*16.
__device__ __forceinline__ void async_cp16(const ushort* g, ushort* l) {
    __builtin_amdgcn_global_load_lds(
        (const __attribute__((address_space(1))) void*)g,
        (__attribute__((address_space(3))) void*)l, 16, 0, 0);
}

// pack two f32 -> one u32 of 2 bf16 (lo = first arg), RNE
__device__ __forceinline__ unsigned int cvt_pk_bf16(float lo, float hi) {
    unsigned int d;
    asm volatile("v_cvt_pk_bf16_f32 %0, %1, %2" : "=v"(d) : "v"(lo), "v"(hi));
    return d;
}
// after: a' = [a.lo32 | b.lo32], b' = [a.hi32 | b.hi32]
__device__ __forceinline__ void pl32swap(unsigned int& a, unsigned int& b) {
    asm volatile("v_permlane32_swap_b32 %0, %1" : "+v"(a), "+v"(b));
}

// ---------------------------------------------------------------------------
// Dtype detector: valid bf16 inputs never have exponent bits 0xFF; fp32 read
// as u16 halves hits 0xFF with p~1/256. flag=1 -> fp32 inputs, 0 -> bf16.
// ---------------------------------------------------------------------------
__global__ __launch_bounds__(256) void detect_kernel(const ushort* __restrict__ x,
                                                     int* __restrict__ flag) {
    __shared__ int any;
    int tid = threadIdx.x;
    if (tid == 0) any = 0;
    __syncthreads();
    int cnt = 0;
    for (int j = 0; j < 64; ++j) {
        ushort u = x[tid * 64 + j];
        if (((u >> 7) & 0xFF) == 0xFF) cnt++;
    }
    if (cnt) atomicOr(&any, 1);
    __syncthreads();
    if (tid == 0) *flag = any ? 1 : 0;
}

// ---------------------------------------------------------------------------
// Merged prep: grid (16,16,6).
//   z in 0..3 : convert + transpose weight z (Q/K/V -> Wqkvt slices, O -> Wot)
//   z == 4   : canonicalize x -> bf16 (4M elems)
//   z == 5   : biases -> fp32 (first 16 blocks)
// ---------------------------------------------------------------------------
__global__ __launch_bounds__(256) void prep_kernel(const void* __restrict__ x,
                                                   const void* __restrict__ Wq,
                                                   const void* __restrict__ Wk,
                                                   const void* __restrict__ Wv,
                                                   const void* __restrict__ Wo,
                                                   const void* __restrict__ bq,
                                                   const void* __restrict__ bk,
                                                   const void* __restrict__ bv,
                                                   const void* __restrict__ bo,
                                                   ushort* __restrict__ xc,
                                                   ushort* __restrict__ Wqkvt,
                                                   ushort* __restrict__ Wot,
                                                   float* __restrict__ biasf,
                                                   const int* __restrict__ flag) {
    int tid = threadIdx.x;
    int z = blockIdx.z;
    bool isf32 = (*flag != 0);

    if (z == 4) {
        int t = (blockIdx.y * 16 + blockIdx.x) * 256 + tid;   // 0..65535
#pragma unroll
        for (int c = 0; c < 8; ++c) {
            int i = t + c * 65536;                            // elem8 index
            if (isf32) {
                const float* s = (const float*)x;
                f32x4 a = *(const f32x4*)&s[(size_t)i * 8];
                f32x4 b = *(const f32x4*)&s[(size_t)i * 8 + 4];
                bf16x8 o;
                o[0] = f2bf(a.x); o[1] = f2bf(a.y); o[2] = f2bf(a.z); o[3] = f2bf(a.w);
                o[4] = f2bf(b.x); o[5] = f2bf(b.y); o[6] = f2bf(b.z); o[7] = f2bf(b.w);
                *(bf16x8*)&xc[(size_t)i * 8] = o;
            } else {
                *(bf16x8*)&xc[(size_t)i * 8] =
                    *(const bf16x8*)&((const ushort*)x)[(size_t)i * 8];
            }
        }
        return;
    }
    if (z == 5) {
        int bid = blockIdx.y * 16 + blockIdx.x;
        if (bid >= 16) return;
        int i = bid * 256 + tid;                              // 0..4095
        int w = i >> 10, j = i & 1023;
        const void* s = (w == 0) ? bq : (w == 1) ? bk : (w == 2) ? bv : bo;
        biasf[i] = isf32 ? ((const float*)s)[j] : bf2f(((const ushort*)s)[j]);
        return;
    }

    // weight transpose
    __shared__ ushort tile[64][72];
    const void* src = (z == 0) ? Wq : (z == 1) ? Wk : (z == 2) ? Wv : Wo;
    ushort* dst = (z < 3) ? (Wqkvt + (size_t)z * D_DIM * D_DIM) : Wot;
    int r0 = blockIdx.y * 64, c0 = blockIdx.x * 64;
#pragma unroll
    for (int p = 0; p < 2; ++p) {
        int r = p * 32 + (tid >> 3);
        int c = (tid & 7) * 8;
        if (isf32) {
            const float* s = (const float*)src;
            f32x4 a = *(const f32x4*)&s[(size_t)(r0 + r) * D_DIM + c0 + c];
            f32x4 b = *(const f32x4*)&s[(size_t)(r0 + r) * D_DIM + c0 + c + 4];
            tile[r][c + 0] = f2bf(a.x); tile[r][c + 1] = f2bf(a.y);
            tile[r][c + 2] = f2bf(a.z); tile[r][c + 3] = f2bf(a.w);
            tile[r][c + 4] = f2bf(b.x); tile[r][c + 5] = f2bf(b.y);
            tile[r][c + 6] = f2bf(b.z); tile[r][c + 7] = f2bf(b.w);
        } else {
            *(bf16x8*)&tile[r][c] =
                *(const bf16x8*)&((const ushort*)src)[(size_t)(r0 + r) * D_DIM + c0 + c];
        }
    }
    __syncthreads();
#pragma unroll
    for (int p = 0; p < 2; ++p) {
        int n  = p * 32 + (tid >> 3);
        int cc = (tid & 7) * 8;
        bf16x8 v;
#pragma unroll
        for (int e = 0; e < 8; ++e) v[e] = (short)tile[cc + e][n];
        *(bf16x8*)&dst[(size_t)(c0 + n) * D_DIM + r0 + cc] = v;
    }
}

// ---------------------------------------------------------------------------
// Fused QKV GEMM: 128x128 tile, BK=64, global_load_lds(16B), XOR swizzle
// (0 bank conflicts). Ncols=3072. Q slice pre-scaled by 0.125*log2(e);
// Q/K slices -> (BH,S,64) bf16; V slice -> TRANSPOSED (BH,64,S) bf16 directly
// (packed 8B stores; 16 rows x 32B per wave-store: L2-merged).
// ---------------------------------------------------------------------------
__global__ __launch_bounds__(256) void gemm128_kernel(const ushort* __restrict__ A,
                                                      const ushort* __restrict__ Bt,
                                                      const float* __restrict__ bias,
                                                      ushort* __restrict__ qkout,
                                                      ushort* __restrict__ vtout) {
    __shared__ ushort As[128 * 64];   // 16 KiB, unpadded
    __shared__ ushort Bs[128 * 64];
    int tid  = threadIdx.x;
    int wave = tid >> 6;
    int lane = tid & 63;
    int l16  = lane & 15;
    int quad = lane >> 4;
    int m0   = blockIdx.y * 128;
    int n0   = blockIdx.x * 128;
    int wm   = wave >> 1;
    int wn   = wave & 1;
    const int K = 1024;

    f32x4 acc[4][4];
#pragma unroll
    for (int i = 0; i < 4; ++i)
#pragma unroll
        for (int j = 0; j < 4; ++j) acc[i][j] = (f32x4){0.f, 0.f, 0.f, 0.f};

    int lrow = lane >> 3;                         // 0..7 row within chunk
    int gcol = ((lane & 7) ^ lrow) * 8;           // swizzled column (elems)
    int sw   = l16 & 7;                           // fragment-read swizzle

    for (int kt = 0; kt < 16; ++kt) {
        int k0 = kt * 64;
#pragma unroll
        for (int j = 0; j < 4; ++j) {
            int chunk = wave * 4 + j;             // 0..15; 8 rows each
            int grow  = chunk * 8 + lrow;
            async_cp16(&A[(size_t)(m0 + grow) * K + k0 + gcol], &As[chunk * 512]);
            async_cp16(&Bt[(size_t)(n0 + grow) * K + k0 + gcol], &Bs[chunk * 512]);
        }
        __syncthreads();

#pragma unroll
        for (int kb = 0; kb < 2; ++kb) {
            bf16x8 af[4], bf[4];
#pragma unroll
            for (int i = 0; i < 4; ++i)
                af[i] = *(const bf16x8*)&As[(wm * 64 + i * 16 + l16) * 64 +
                                            (((kb * 4 + quad) ^ sw) << 3)];
#pragma unroll
            for (int j = 0; j < 4; ++j)
                bf[j] = *(const bf16x8*)&Bs[(wn * 64 + j * 16 + l16) * 64 +
                                            (((kb * 4 + quad) ^ sw) << 3)];
#pragma unroll
            for (int i = 0; i < 4; ++i)
#pragma unroll
                for (int j = 0; j < 4; ++j)
                    acc[i][j] = __builtin_amdgcn_mfma_f32_16x16x32_bf16(af[i], bf[j],
                                                                        acc[i][j], 0, 0, 0);
        }
        __syncthreads();
    }

    const size_t TSZ = (size_t)B_DIM * H_DIM * S_DIM * HD_DIM;   // 4 Mi elems
#pragma unroll
    for (int j = 0; j < 4; ++j) {
        int n = n0 + wn * 64 + j * 16 + l16;        // C/D col = lane&15
        float bv = bias[n];
        int which = n >> 10;                        // 0=Q 1=K 2=V
        int n1 = n & 1023;
        int h = n1 >> 6, hd = n1 & 63;
#pragma unroll
        for (int i = 0; i < 4; ++i) {
            int mb = m0 + wm * 64 + i * 16 + quad * 4;     // row base (quad*4)
            int b = mb >> 11, s = mb & (S_DIM - 1);
            float v4[4];
#pragma unroll
            for (int r = 0; r < 4; ++r) v4[r] = acc[i][j][r] + bv;
            if (which == 2) {
                // V -> transposed (BH,64,S): 4 consecutive s, packed 8B store
                ushort pk[4];
#pragma unroll
                for (int r = 0; r < 4; ++r) pk[r] = f2bf(v4[r]);
                *(uint2*)&vtout[(((size_t)(b * H_DIM + h) * HD_DIM + hd)) * S_DIM + s] =
                    *(uint2*)pk;
            } else {
#pragma unroll
                for (int r = 0; r < 4; ++r) {
                    float v = v4[r];
                    // fold softmax scale AND log2(e) into Q (attn uses exp2)
                    if (which == 0) v *= 0.18033688011f;   // 0.125 * log2(e)
                    qkout[which * TSZ +
                          ((((size_t)(b * H_DIM + h)) * S_DIM + s + r) << 6) + hd] = f2bf(v);
                }
            }
        }
    }
}

// ---------------------------------------------------------------------------
// O-projection GEMM: 64x128 tile (M x N), BK=64, same staging/swizzle.
// ---------------------------------------------------------------------------
__global__ __launch_bounds__(256) void gemm64_kernel(const ushort* __restrict__ A,
                                                     const ushort* __restrict__ Bt,
                                                     const float* __restrict__ bias,
                                                     void* __restrict__ out,
                                                     const int* __restrict__ flag) {
    __shared__ ushort As[64 * 64];    // 8 KiB
    __shared__ ushort Bs[128 * 64];   // 16 KiB
    int tid  = threadIdx.x;
    int wave = tid >> 6;
    int lane = tid & 63;
    int l16  = lane & 15;
    int quad = lane >> 4;
    int m0   = blockIdx.y * 64;
    int n0   = blockIdx.x * 128;
    const int K = 1024;

    f32x4 acc[4][2];
#pragma unroll
    for (int i = 0; i < 4; ++i)
#pragma unroll
        for (int j = 0; j < 2; ++j) acc[i][j] = (f32x4){0.f, 0.f, 0.f, 0.f};

    int lrow = lane >> 3;
    int gcol = ((lane & 7) ^ lrow) * 8;
    int sw   = l16 & 7;

    for (int kt = 0; kt < 16; ++kt) {
        int k0 = kt * 64;
        // A: 8 chunks (2 per wave); B: 16 chunks (4 per wave)
#pragma unroll
        for (int j = 0; j < 2; ++j) {
            int chunk = wave * 2 + j;
            int grow  = chunk * 8 + lrow;
            async_cp16(&A[(size_t)(m0 + grow) * K + k0 + gcol], &As[chunk * 512]);
        }
#pragma unroll
        for (int j = 0; j < 4; ++j) {
            int chunk = wave * 4 + j;
            int grow  = chunk * 8 + lrow;
            async_cp16(&Bt[(size_t)(n0 + grow) * K + k0 + gcol], &Bs[chunk * 512]);
        }
        __syncthreads();

#pragma unroll
        for (int kb = 0; kb < 2; ++kb) {
            bf16x8 af[4], bf[2];
#pragma unroll
            for (int i = 0; i < 4; ++i)
                af[i] = *(const bf16x8*)&As[(i * 16 + l16) * 64 +
                                            (((kb * 4 + quad) ^ sw) << 3)];
#pragma unroll
            for (int j = 0; j < 2; ++j)
                bf[j] = *(const bf16x8*)&Bs[(wave * 32 + j * 16 + l16) * 64 +
                                            (((kb * 4 + quad) ^ sw) << 3)];
#pragma unroll
            for (int i = 0; i < 4; ++i)
#pragma unroll
                for (int j = 0; j < 2; ++j)
                    acc[i][j] = __builtin_amdgcn_mfma_f32_16x16x32_bf16(af[i], bf[j],
                                                                        acc[i][j], 0, 0, 0);
        }
        __syncthreads();
    }

    int outf32 = *flag;
#pragma unroll
    for (int j = 0; j < 2; ++j) {
        int n = n0 + wave * 32 + j * 16 + l16;
        float bv = bias[n];
#pragma unroll
        for (int i = 0; i < 4; ++i)
#pragma unroll
            for (int r = 0; r < 4; ++r) {
                int m = m0 + i * 16 + quad * 4 + r;
                float v = acc[i][j][r] + bv;
                if (outf32) ((float*)out)[(size_t)m * D_DIM + n] = v;
                else        ((ushort*)out)[(size_t)m * D_DIM + n] = f2bf(v);
            }
    }
}

// ---------------------------------------------------------------------------
// Causal attention v4: flash-decoding key-split for uniform occupancy.
// R3 counters showed the bottleneck is work distribution, not LDS BW:
// Occupancy 10.8% (3.5 waves/CU) because the short/long block pairing left
// CUs running a single 4-wave block most of the time. Softmax here has no
// running max, so partials combine linearly: split each (bh,qt) job into
// TWO key-range halves of exactly qt+1 64-key tiles -> 1024 blocks, lengths
// 1..16 rounds, dispatched long-first; HW backfills as blocks retire.
// Each block writes raw (unnormalized) O partial f32 + rsum f32; a combine
// kernel normalizes. 32x32x16 MFMA structure, in-register P transpose,
// async global_load_lds double-buffer staging all kept from v3.
// Per-wave generalized causal handling: skip tile if k0 > qmax; mask if
// k0+63 > qmin.
// Q (pre-scaled 0.125*log2e), K: (BH,S,64) bf16.  Vt: (BH,64,S) bf16.
// ---------------------------------------------------------------------------
__global__ __launch_bounds__(256, 4) void attn_kernel(const ushort* __restrict__ Qg,
                                                      const ushort* __restrict__ Kg,
                                                      const ushort* __restrict__ Vt,
                                                      float* __restrict__ pO0,
                                                      float* __restrict__ pO1,
                                                      float* __restrict__ Rsum) {
    __shared__ ushort Ks[2][64 * 64];   // 16 KiB (double buffer)
    __shared__ ushort Vs[2][64 * 64];   // 16 KiB
    int tid  = threadIdx.x;
    int wave = tid >> 6;
    int lane = tid & 63;
    int l31  = lane & 31;
    int hi   = lane >> 5;
    int sw7  = lane & 7;
    int bh   = blockIdx.x;
    int y    = blockIdx.y;              // 0..31, long-first
    int qt   = 15 - (y >> 1);
    int half = y & 1;
    int nt2  = qt + 1;                  // tiles per half-job
    int t_lo = half * nt2;
    int t_hi = t_lo + nt2;
    int q0   = qt * 128;

    const ushort* Qb = Qg + (size_t)bh * S_DIM * HD_DIM;
    const ushort* Kb = Kg + (size_t)bh * S_DIM * HD_DIM;
    const ushort* Vb = Vt + (size_t)bh * HD_DIM * S_DIM;

    // Q fragments (B-operand: n=query=l31, k=hd = kk*16 + hi*8 + e)
    bf16x8 qf[4];
#pragma unroll
    for (int kk = 0; kk < 4; ++kk)
        qf[kk] = *(const bf16x8*)&Qb[(size_t)(q0 + wave * 32 + l31) * HD_DIM +
                                     kk * 16 + hi * 8];

    f32x16 o[2];
#pragma unroll
    for (int n = 0; n < 2; ++n)
#pragma unroll
        for (int r = 0; r < 16; ++r) o[n][r] = 0.f;
    float rsum = 0.f;

    int lrow = lane >> 3;                 // staging row within 8-row chunk
    int gcol = ((lane & 7) ^ lrow) * 8;   // swizzled source column (elems)
    int qmin = q0 + wave * 32;            // smallest query this wave owns

    // stage tile t_lo -> buf 0 (2 cp16 K + 2 cp16 V per thread)
    {
        int kst = t_lo * 64;
#pragma unroll
        for (int j = 0; j < 2; ++j) {
            int chunk = wave * 2 + j;
            int grow  = chunk * 8 + lrow;
            async_cp16(&Kb[(size_t)(kst + grow) * HD_DIM + gcol], &Ks[0][chunk * 512]);
            async_cp16(&Vb[(size_t)grow * S_DIM + kst + gcol], &Vs[0][chunk * 512]);
        }
    }

    int p = 0;
    for (int t = t_lo; t < t_hi; ++t) {
        // implicit vmcnt(0) drain + barrier: tile t visible, buf p^1 free
        __syncthreads();
        if (t + 1 < t_hi) {
            int k1 = (t + 1) * 64;
#pragma unroll
            for (int j = 0; j < 2; ++j) {
                int chunk = wave * 2 + j;
                int grow  = chunk * 8 + lrow;
                async_cp16(&Kb[(size_t)(k1 + grow) * HD_DIM + gcol],
                           &Ks[p ^ 1][chunk * 512]);
                async_cp16(&Vb[(size_t)grow * S_DIM + k1 + gcol],
                           &Vs[p ^ 1][chunk * 512]);
            }
        }
        int k0 = t * 64;

        // tile fully masked for this wave (all keys > its max query): skip
        if (k0 <= qmin + 31) {
            // ---- S^T = K Q^T (A=K rows mb*32+l31, k-chunk 2j+hi) ----
            f32x16 sc[2];
#pragma unroll
            for (int n = 0; n < 2; ++n)
#pragma unroll
                for (int r = 0; r < 16; ++r) sc[n][r] = 0.f;
            __builtin_amdgcn_s_setprio(1);
#pragma unroll
            for (int j = 0; j < 4; ++j)
#pragma unroll
                for (int mb = 0; mb < 2; ++mb) {
                    bf16x8 kf = *(const bf16x8*)&Ks[p][(mb * 32 + l31) * 64 +
                                                       (((2 * j + hi) ^ sw7) << 3)];
                    sc[mb] = __builtin_amdgcn_mfma_f32_32x32x16_bf16(kf, qf[j],
                                                                     sc[mb], 0, 0, 0);
                }
            __builtin_amdgcn_s_setprio(0);

            // ---- hoist V B-frags (overlap the softmax VALU chain) ----
            bf16x8 vf[4][2];
#pragma unroll
            for (int j = 0; j < 4; ++j)
#pragma unroll
                for (int nb = 0; nb < 2; ++nb)
                    vf[j][nb] = *(const bf16x8*)&Vs[p][(nb * 32 + l31) * 64 +
                                                       (((2 * j + hi) ^ sw7) << 3)];

            // ---- causal mask: tile spans the diagonal for this wave ----
            if (k0 + 63 > qmin) {
                int qglob = qmin + l31;
#pragma unroll
                for (int mb = 0; mb < 2; ++mb)
#pragma unroll
                    for (int r = 0; r < 16; ++r) {
                        int key = k0 + mb * 32 + (r & 3) + 8 * (r >> 2) + 4 * hi;
                        if (key > qglob) sc[mb][r] = -1e30f;
                    }
            }

            // ---- exp2 + row-sum + pack + in-register half-swap transpose ----
            bf16x8 pf[4];
#pragma unroll
            for (int mb = 0; mb < 2; ++mb) {
                unsigned int W[8];
#pragma unroll
                for (int g = 0; g < 4; ++g) {
                    float e0 = __builtin_amdgcn_exp2f(sc[mb][4 * g + 0]);
                    float e1 = __builtin_amdgcn_exp2f(sc[mb][4 * g + 1]);
                    float e2 = __builtin_amdgcn_exp2f(sc[mb][4 * g + 2]);
                    float e3 = __builtin_amdgcn_exp2f(sc[mb][4 * g + 3]);
                    rsum += (e0 + e1) + (e2 + e3);
                    W[2 * g]     = cvt_pk_bf16(e0, e1);
                    W[2 * g + 1] = cvt_pk_bf16(e2, e3);
                }
                // lo-lane holds keys {8g..8g+3}; hi-lane +4. Swap lo/hi halves
                // pairwise to form A-frag key order 0..15.
                pl32swap(W[0], W[2]); pl32swap(W[1], W[3]);
                pl32swap(W[4], W[6]); pl32swap(W[5], W[7]);
                union { unsigned int u[4]; bf16x8 v; } c0, c1;
                c0.u[0] = W[0]; c0.u[1] = W[1]; c0.u[2] = W[2]; c0.u[3] = W[3];
                c1.u[0] = W[4]; c1.u[1] = W[5]; c1.u[2] = W[6]; c1.u[3] = W[7];
                pf[2 * mb]     = c0.v;
                pf[2 * mb + 1] = c1.v;
            }

            // ---- PV: O += P.V (A=pf, B=V frags in regs) ----
            __builtin_amdgcn_s_setprio(1);
#pragma unroll
            for (int j = 0; j < 4; ++j)
#pragma unroll
                for (int nb = 0; nb < 2; ++nb)
                    o[nb] = __builtin_amdgcn_mfma_f32_32x32x16_bf16(pf[j], vf[j][nb],
                                                                    o[nb], 0, 0, 0);
            __builtin_amdgcn_s_setprio(0);
        }
        p ^= 1;
    }

    // row sum across the two key-halves held by lanes l and l+32
    rsum += __shfl_xor(rsum, 32, 64);

    // epilogue: RAW partial O (f32) + partial rsum; combine kernel normalizes
    float* pO = half ? pO1 : pO0;
    int b = bh >> 4, h = bh & 15;
#pragma unroll
    for (int nb = 0; nb < 2; ++nb)
#pragma unroll
        for (int r = 0; r < 16; ++r) {
            int qrow = (r & 3) + 8 * (r >> 2) + 4 * hi;
            int q = q0 + wave * 32 + qrow;
            pO[(size_t)(b * S_DIM + q) * D_DIM + h * HD_DIM + nb * 32 + l31] = o[nb][r];
        }
    if (lane < 32)
        Rsum[half * (32 * S_DIM) + bh * S_DIM + qmin + lane] = rsum;
}

// ---------------------------------------------------------------------------
// Combine: attn = bf16((pO0 + pO1) / (r0 + r1)), elementwise over (B,S,D).
// One thread = 8 contiguous d within one head -> single rsum pair.
// ---------------------------------------------------------------------------
__global__ __launch_bounds__(256) void combine_kernel(const float* __restrict__ pO0,
                                                      const float* __restrict__ pO1,
                                                      const float* __restrict__ Rsum,
                                                      ushort* __restrict__ attn) {
    int e8 = blockIdx.x * 256 + threadIdx.x;      // 0..524287
    int d8 = e8 & 127;                            // D/8 index
    int s  = (e8 >> 7) & (S_DIM - 1);
    int b  = e8 >> 18;
    int bh = b * H_DIM + (d8 >> 3);
    float r0 = Rsum[bh * S_DIM + s];
    float r1 = Rsum[32 * S_DIM + bh * S_DIM + s];
    float inv = 1.f / (r0 + r1);
    size_t base = (size_t)e8 * 8;
    f32x4 a0 = *(const f32x4*)&pO0[base];
    f32x4 a1 = *(const f32x4*)&pO0[base + 4];
    f32x4 c0 = *(const f32x4*)&pO1[base];
    f32x4 c1 = *(const f32x4*)&pO1[base + 4];
    bf16x8 ov;
    ov[0] = f2bf((a0.x + c0.x) * inv); ov[1] = f2bf((a0.y + c0.y) * inv);
    ov[2] = f2bf((a0.z + c0.z) * inv); ov[3] = f2bf((a0.w + c0.w) * inv);
    ov[4] = f2bf((a1.x + c1.x) * inv); ov[5] = f2bf((a1.y + c1.y) * inv);
    ov[6] = f2bf((a1.z + c1.z) * inv); ov[7] = f2bf((a1.w + c1.w) * inv);
    *(bf16x8*)&attn[base] = ov;
}

// ---------------------------------------------------------------------------
extern "C" void kernel_launch(void* const* d_in, const int* in_sizes, int n_in,
                              void* d_out, int out_size, void* d_ws, size_t ws_size,
                              hipStream_t stream) {
    const void* x  = d_in[0];
    const void* Wq = d_in[1];
    const void* bq = d_in[2];
    const void* Wk = d_in[3];
    const void* bk = d_in[4];
    const void* Wv = d_in[5];
    const void* bv = d_in[6];
    const void* Wo = d_in[7];
    const void* bo = d_in[8];
    // d_in[9] = mask: exactly causal tril, handled analytically.

    char* ws = (char*)d_ws;
    const size_t MB = 1024 * 1024;
    const size_t base = 64 * 1024;
    int*    flag   = (int*)ws;
    float*  biasf  = (float*)(ws + 4096);
    ushort* xc     = (ushort*)(ws + base);                  // 8 MiB; reused as attn later
    ushort* Wqkvt  = (ushort*)(ws + base + 8  * MB);        // 6 MiB (3072x1024)
    ushort* Wot    = (ushort*)(ws + base + 14 * MB);        // 2 MiB
    ushort* Qc     = (ushort*)(ws + base + 16 * MB);        // Q,K slices (BH,S,64)
    ushort* Vtp    = (ushort*)(ws + base + 40 * MB);        // 8 MiB (BH,64,S), direct
    float*  pO0    = (float*)(ws + base + 48 * MB);         // 16 MiB f32 partial
    float*  pO1    = (float*)(ws + base + 64 * MB);         // 16 MiB f32 partial
    float*  Rsum   = (float*)(ws + base + 80 * MB);         // 512 KiB (2x32x2048)
    ushort* attn   = xc;                                    // xc dead before combine writes

    dim3 tb(256);

    detect_kernel<<<1, tb, 0, stream>>>((const ushort*)x, flag);

    dim3 pg(16, 16, 6);
    prep_kernel<<<pg, tb, 0, stream>>>(x, Wq, Wk, Wv, Wo, bq, bk, bv, bo,
                                       xc, Wqkvt, Wot, biasf, flag);

    // Fused QKV projection: (4096x1024) x (3072x1024)^T; V written transposed
    dim3 gq(3 * D_DIM / 128, (B_DIM * S_DIM) / 128);   // (24, 32)
    gemm128_kernel<<<gq, tb, 0, stream>>>(xc, Wqkvt, biasf, Qc, Vtp);

    dim3 ag(B_DIM * H_DIM, 32);                        // (32, 32) = 1024 half-jobs
    attn_kernel<<<ag, tb, 0, stream>>>(Qc, Qc + (size_t)B_DIM * H_DIM * S_DIM * HD_DIM,
                                       Vtp, pO0, pO1, Rsum);

    combine_kernel<<<2048, tb, 0, stream>>>(pO0, pO1, Rsum, attn);

    dim3 go(D_DIM / 128, (B_DIM * S_DIM) / 64);        // (8, 64) = 512 blocks
    gemm64_kernel<<<go, tb, 0, stream>>>(attn, Wot, biasf + 3072, d_out, flag);
}

// Round 5
// 195.722 us; speedup vs baseline: 1.0337x; 1.0337x over previous
//
#include <hip/hip_runtime.h>
#include <hip/hip_bf16.h>

typedef __attribute__((ext_vector_type(8))) short bf16x8;
typedef __attribute__((ext_vector_type(4))) float f32x4;
typedef __attribute__((ext_vector_type(16))) float f32x16;

#define B_DIM  2
#define S_DIM  2048
#define D_DIM  1024
#define H_DIM  16
#define HD_DIM 64

__device__ __forceinline__ float bf2f(ushort u) {
    union { unsigned int ui; float f; } c; c.ui = ((unsigned int)u) << 16; return c.f;
}
__device__ __forceinline__ ushort f2bf(float f) {
    __hip_bfloat16 h = __float2bfloat16(f);
    return *reinterpret_cast<ushort*>(&h);
}

// Async global->LDS DMA, 16 B per lane. LDS dest = wave-uniform base + lane*16.
__device__ __forceinline__ void async_cp16(const ushort* g, ushort* l) {
    __builtin_amdgcn_global_load_lds(
        (const __attribute__((address_space(1))) void*)g,
        (__attribute__((address_space(3))) void*)l, 16, 0, 0);
}

// pack two f32 -> one u32 of 2 bf16 (lo = first arg), RNE
__device__ __forceinline__ unsigned int cvt_pk_bf16(float lo, float hi) {
    unsigned int d;
    asm volatile("v_cvt_pk_bf16_f32 %0, %1, %2" : "=v"(d) : "v"(lo), "v"(hi));
    return d;
}
// after: a' = [a.lo32 | b.lo32], b' = [a.hi32 | b.hi32]
__device__ __forceinline__ void pl32swap(unsigned int& a, unsigned int& b) {
    asm volatile("v_permlane32_swap_b32 %0, %1" : "+v"(a), "+v"(b));
}

// ---------------------------------------------------------------------------
// Dtype detector: valid bf16 inputs never have exponent bits 0xFF; fp32 read
// as u16 halves hits 0xFF with p~1/256. flag=1 -> fp32 inputs, 0 -> bf16.
// ---------------------------------------------------------------------------
__global__ __launch_bounds__(256) void detect_kernel(const ushort* __restrict__ x,
                                                     int* __restrict__ flag) {
    __shared__ int any;
    int tid = threadIdx.x;
    if (tid == 0) any = 0;
    __syncthreads();
    int cnt = 0;
    for (int j = 0; j < 64; ++j) {
        ushort u = x[tid * 64 + j];
        if (((u >> 7) & 0xFF) == 0xFF) cnt++;
    }
    if (cnt) atomicOr(&any, 1);
    __syncthreads();
    if (tid == 0) *flag = any ? 1 : 0;
}

// ---------------------------------------------------------------------------
// Merged prep: grid (16,16,6).
//   z in 0..3 : convert + transpose weight z (Q/K/V -> Wqkvt slices, O -> Wot)
//   z == 4   : canonicalize x -> bf16 (4M elems)
//   z == 5   : biases -> fp32 (first 16 blocks)
// ---------------------------------------------------------------------------
__global__ __launch_bounds__(256) void prep_kernel(const void* __restrict__ x,
                                                   const void* __restrict__ Wq,
                                                   const void* __restrict__ Wk,
                                                   const void* __restrict__ Wv,
                                                   const void* __restrict__ Wo,
                                                   const void* __restrict__ bq,
                                                   const void* __restrict__ bk,
                                                   const void* __restrict__ bv,
                                                   const void* __restrict__ bo,
                                                   ushort* __restrict__ xc,
                                                   ushort* __restrict__ Wqkvt,
                                                   ushort* __restrict__ Wot,
                                                   float* __restrict__ biasf,
                                                   const int* __restrict__ flag) {
    int tid = threadIdx.x;
    int z = blockIdx.z;
    bool isf32 = (*flag != 0);

    if (z == 4) {
        int t = (blockIdx.y * 16 + blockIdx.x) * 256 + tid;   // 0..65535
#pragma unroll
        for (int c = 0; c < 8; ++c) {
            int i = t + c * 65536;                            // elem8 index
            if (isf32) {
                const float* s = (const float*)x;
                f32x4 a = *(const f32x4*)&s[(size_t)i * 8];
                f32x4 b = *(const f32x4*)&s[(size_t)i * 8 + 4];
                bf16x8 o;
                o[0] = f2bf(a.x); o[1] = f2bf(a.y); o[2] = f2bf(a.z); o[3] = f2bf(a.w);
                o[4] = f2bf(b.x); o[5] = f2bf(b.y); o[6] = f2bf(b.z); o[7] = f2bf(b.w);
                *(bf16x8*)&xc[(size_t)i * 8] = o;
            } else {
                *(bf16x8*)&xc[(size_t)i * 8] =
                    *(const bf16x8*)&((const ushort*)x)[(size_t)i * 8];
            }
        }
        return;
    }
    if (z == 5) {
        int bid = blockIdx.y * 16 + blockIdx.x;
        if (bid >= 16) return;
        int i = bid * 256 + tid;                              // 0..4095
        int w = i >> 10, j = i & 1023;
        const void* s = (w == 0) ? bq : (w == 1) ? bk : (w == 2) ? bv : bo;
        biasf[i] = isf32 ? ((const float*)s)[j] : bf2f(((const ushort*)s)[j]);
        return;
    }

    // weight transpose
    __shared__ ushort tile[64][72];
    const void* src = (z == 0) ? Wq : (z == 1) ? Wk : (z == 2) ? Wv : Wo;
    ushort* dst = (z < 3) ? (Wqkvt + (size_t)z * D_DIM * D_DIM) : Wot;
    int r0 = blockIdx.y * 64, c0 = blockIdx.x * 64;
#pragma unroll
    for (int p = 0; p < 2; ++p) {
        int r = p * 32 + (tid >> 3);
        int c = (tid & 7) * 8;
        if (isf32) {
            const float* s = (const float*)src;
            f32x4 a = *(const f32x4*)&s[(size_t)(r0 + r) * D_DIM + c0 + c];
            f32x4 b = *(const f32x4*)&s[(size_t)(r0 + r) * D_DIM + c0 + c + 4];
            tile[r][c + 0] = f2bf(a.x); tile[r][c + 1] = f2bf(a.y);
            tile[r][c + 2] = f2bf(a.z); tile[r][c + 3] = f2bf(a.w);
            tile[r][c + 4] = f2bf(b.x); tile[r][c + 5] = f2bf(b.y);
            tile[r][c + 6] = f2bf(b.z); tile[r][c + 7] = f2bf(b.w);
        } else {
            *(bf16x8*)&tile[r][c] =
                *(const bf16x8*)&((const ushort*)src)[(size_t)(r0 + r) * D_DIM + c0 + c];
        }
    }
    __syncthreads();
#pragma unroll
    for (int p = 0; p < 2; ++p) {
        int n  = p * 32 + (tid >> 3);
        int cc = (tid & 7) * 8;
        bf16x8 v;
#pragma unroll
        for (int e = 0; e < 8; ++e) v[e] = (short)tile[cc + e][n];
        *(bf16x8*)&dst[(size_t)(c0 + n) * D_DIM + r0 + cc] = v;
    }
}

// ---------------------------------------------------------------------------
// Fused QKV GEMM: 128x128 tile, BK=64, global_load_lds(16B), XOR swizzle.
// Q -> (BH,S,64) bf16 (pre-scaled 0.125*log2e).
// K -> FRAGMENT-PACKED Kp[bh][t][mb][jm][hi][l31][e]: attn reads one coalesced
//      1KB dwordx4 per (mb,jm) fragment straight from L2, no LDS.
// V -> FRAGMENT-PACKED Vp[bh][t][j][nb][hi][l31][e] (uint2 stores preserved).
// ---------------------------------------------------------------------------
__global__ __launch_bounds__(256) void gemm128_kernel(const ushort* __restrict__ A,
                                                      const ushort* __restrict__ Bt,
                                                      const float* __restrict__ bias,
                                                      ushort* __restrict__ qout,
                                                      ushort* __restrict__ kpout,
                                                      ushort* __restrict__ vpout) {
    __shared__ ushort As[128 * 64];   // 16 KiB, unpadded
    __shared__ ushort Bs[128 * 64];
    int tid  = threadIdx.x;
    int wave = tid >> 6;
    int lane = tid & 63;
    int l16  = lane & 15;
    int quad = lane >> 4;
    int m0   = blockIdx.y * 128;
    int n0   = blockIdx.x * 128;
    int wm   = wave >> 1;
    int wn   = wave & 1;
    const int K = 1024;

    f32x4 acc[4][4];
#pragma unroll
    for (int i = 0; i < 4; ++i)
#pragma unroll
        for (int j = 0; j < 4; ++j) acc[i][j] = (f32x4){0.f, 0.f, 0.f, 0.f};

    int lrow = lane >> 3;                         // 0..7 row within chunk
    int gcol = ((lane & 7) ^ lrow) * 8;           // swizzled column (elems)
    int sw   = l16 & 7;                           // fragment-read swizzle

    for (int kt = 0; kt < 16; ++kt) {
        int k0 = kt * 64;
#pragma unroll
        for (int j = 0; j < 4; ++j) {
            int chunk = wave * 4 + j;             // 0..15; 8 rows each
            int grow  = chunk * 8 + lrow;
            async_cp16(&A[(size_t)(m0 + grow) * K + k0 + gcol], &As[chunk * 512]);
            async_cp16(&Bt[(size_t)(n0 + grow) * K + k0 + gcol], &Bs[chunk * 512]);
        }
        __syncthreads();

#pragma unroll
        for (int kb = 0; kb < 2; ++kb) {
            bf16x8 af[4], bf[4];
#pragma unroll
            for (int i = 0; i < 4; ++i)
                af[i] = *(const bf16x8*)&As[(wm * 64 + i * 16 + l16) * 64 +
                                            (((kb * 4 + quad) ^ sw) << 3)];
#pragma unroll
            for (int j = 0; j < 4; ++j)
                bf[j] = *(const bf16x8*)&Bs[(wn * 64 + j * 16 + l16) * 64 +
                                            (((kb * 4 + quad) ^ sw) << 3)];
#pragma unroll
            for (int i = 0; i < 4; ++i)
#pragma unroll
                for (int j = 0; j < 4; ++j)
                    acc[i][j] = __builtin_amdgcn_mfma_f32_16x16x32_bf16(af[i], bf[j],
                                                                        acc[i][j], 0, 0, 0);
        }
        __syncthreads();
    }

#pragma unroll
    for (int j = 0; j < 4; ++j) {
        int n = n0 + wn * 64 + j * 16 + l16;        // C/D col = lane&15
        float bv = bias[n];
        int which = n >> 10;                        // 0=Q 1=K 2=V
        int n1 = n & 1023;
        int h = n1 >> 6, hd = n1 & 63;
#pragma unroll
        for (int i = 0; i < 4; ++i) {
            int mb = m0 + wm * 64 + i * 16 + quad * 4;     // row base (quad*4)
            int b = mb >> 11, s = mb & (S_DIM - 1);
            int bh = b * H_DIM + h;
            float v4[4];
#pragma unroll
            for (int r = 0; r < 4; ++r) v4[r] = acc[i][j][r] + bv;
            if (which == 2) {
                // V fragment-packed; s..s+3 contiguous e -> uint2 store
                ushort pk[4];
#pragma unroll
                for (int r = 0; r < 4; ++r) pk[r] = f2bf(v4[r]);
                size_t vidx = (size_t)bh * 131072 + (size_t)(s >> 6) * 4096 +
                              (size_t)((s >> 4) & 3) * 1024 + (size_t)(hd >> 5) * 512 +
                              (size_t)((s >> 3) & 1) * 256 + (size_t)(hd & 31) * 8 +
                              (s & 7);
                *(uint2*)&vpout[vidx] = *(uint2*)pk;
            } else if (which == 1) {
                // K fragment-packed; 4 scalar stores (stride 8 elems)
#pragma unroll
                for (int r = 0; r < 4; ++r) {
                    int key = s + r;
                    size_t kidx = (size_t)bh * 131072 + (size_t)(key >> 6) * 4096 +
                                  (size_t)((key >> 5) & 1) * 2048 +
                                  (size_t)(hd >> 4) * 512 +
                                  (size_t)((hd >> 3) & 1) * 256 +
                                  (size_t)(key & 31) * 8 + (hd & 7);
                    kpout[kidx] = f2bf(v4[r]);
                }
            } else {
#pragma unroll
                for (int r = 0; r < 4; ++r) {
                    // fold softmax scale AND log2(e) into Q (attn uses exp2)
                    float v = v4[r] * 0.18033688011f;      // 0.125 * log2(e)
                    qout[((((size_t)bh) * S_DIM + s + r) << 6) + hd] = f2bf(v);
                }
            }
        }
    }
}

// ---------------------------------------------------------------------------
// O-projection GEMM: 64x128 tile (M x N), BK=64, same staging/swizzle.
// ---------------------------------------------------------------------------
__global__ __launch_bounds__(256) void gemm64_kernel(const ushort* __restrict__ A,
                                                     const ushort* __restrict__ Bt,
                                                     const float* __restrict__ bias,
                                                     void* __restrict__ out,
                                                     const int* __restrict__ flag) {
    __shared__ ushort As[64 * 64];    // 8 KiB
    __shared__ ushort Bs[128 * 64];   // 16 KiB
    int tid  = threadIdx.x;
    int wave = tid >> 6;
    int lane = tid & 63;
    int l16  = lane & 15;
    int quad = lane >> 4;
    int m0   = blockIdx.y * 64;
    int n0   = blockIdx.x * 128;
    const int K = 1024;

    f32x4 acc[4][2];
#pragma unroll
    for (int i = 0; i < 4; ++i)
#pragma unroll
        for (int j = 0; j < 2; ++j) acc[i][j] = (f32x4){0.f, 0.f, 0.f, 0.f};

    int lrow = lane >> 3;
    int gcol = ((lane & 7) ^ lrow) * 8;
    int sw   = l16 & 7;

    for (int kt = 0; kt < 16; ++kt) {
        int k0 = kt * 64;
        // A: 8 chunks (2 per wave); B: 16 chunks (4 per wave)
#pragma unroll
        for (int j = 0; j < 2; ++j) {
            int chunk = wave * 2 + j;
            int grow  = chunk * 8 + lrow;
            async_cp16(&A[(size_t)(m0 + grow) * K + k0 + gcol], &As[chunk * 512]);
        }
#pragma unroll
        for (int j = 0; j < 4; ++j) {
            int chunk = wave * 4 + j;
            int grow  = chunk * 8 + lrow;
            async_cp16(&Bt[(size_t)(n0 + grow) * K + k0 + gcol], &Bs[chunk * 512]);
        }
        __syncthreads();

#pragma unroll
        for (int kb = 0; kb < 2; ++kb) {
            bf16x8 af[4], bf[2];
#pragma unroll
            for (int i = 0; i < 4; ++i)
                af[i] = *(const bf16x8*)&As[(i * 16 + l16) * 64 +
                                            (((kb * 4 + quad) ^ sw) << 3)];
#pragma unroll
            for (int j = 0; j < 2; ++j)
                bf[j] = *(const bf16x8*)&Bs[(wave * 32 + j * 16 + l16) * 64 +
                                            (((kb * 4 + quad) ^ sw) << 3)];
#pragma unroll
            for (int i = 0; i < 4; ++i)
#pragma unroll
                for (int j = 0; j < 2; ++j)
                    acc[i][j] = __builtin_amdgcn_mfma_f32_16x16x32_bf16(af[i], bf[j],
                                                                        acc[i][j], 0, 0, 0);
        }
        __syncthreads();
    }

    int outf32 = *flag;
#pragma unroll
    for (int j = 0; j < 2; ++j) {
        int n = n0 + wave * 32 + j * 16 + l16;
        float bv = bias[n];
#pragma unroll
        for (int i = 0; i < 4; ++i)
#pragma unroll
            for (int r = 0; r < 4; ++r) {
                int m = m0 + i * 16 + quad * 4 + r;
                float v = acc[i][j][r] + bv;
                if (outf32) ((float*)out)[(size_t)m * D_DIM + n] = v;
                else        ((ushort*)out)[(size_t)m * D_DIM + n] = f2bf(v);
            }
    }
}

// ---------------------------------------------------------------------------
// Causal attention v5: barrier-free, LDS-free per-wave streaming.
// R1-R4 invariant: MfmaUtil pinned ~15%, round ~2000cyc vs ~900cyc chain,
// regardless of occupancy/LDS-traffic/MFMA-shape => co-resident waves were
// PHASE-LOCKED by the per-tile __syncthreads + vmcnt(0) drain (all waves MFMA
// together, all exp2 together -> no complementary overlap; m190 regime).
// Fix: 1 wave per block (64T), K/V read directly from L2 in fragment-packed
// layout (1KB coalesced dwordx4 per fragment), register double-buffered.
// Zero synchronization; 4096 independent jobs (key-split halves, v4 combine).
// ---------------------------------------------------------------------------
#define LOADK(DST, T) { size_t _b = Kbase + (size_t)(T) * 4096 + lane8;           \
    _Pragma("unroll") for (int _i = 0; _i < 8; ++_i)                              \
        DST[_i] = *(const bf16x8*)&Kp[_b + (size_t)((_i >> 2) * 2048 + (_i & 3) * 512)]; }

#define LOADV(DST, T) { size_t _b = Vbase + (size_t)(T) * 4096 + lane8;           \
    _Pragma("unroll") for (int _i = 0; _i < 8; ++_i)                              \
        DST[_i] = *(const bf16x8*)&Vp[_b + (size_t)((_i >> 1) * 1024 + (_i & 1) * 512)]; }

#define SOFT(SC, P0, P1) { unsigned int W[8];                                     \
    _Pragma("unroll") for (int _g = 0; _g < 4; ++_g) {                            \
        float _e0 = __builtin_amdgcn_exp2f(SC[4 * _g + 0]);                       \
        float _e1 = __builtin_amdgcn_exp2f(SC[4 * _g + 1]);                       \
        float _e2 = __builtin_amdgcn_exp2f(SC[4 * _g + 2]);                       \
        float _e3 = __builtin_amdgcn_exp2f(SC[4 * _g + 3]);                       \
        rsum += (_e0 + _e1) + (_e2 + _e3);                                        \
        W[2 * _g]     = cvt_pk_bf16(_e0, _e1);                                    \
        W[2 * _g + 1] = cvt_pk_bf16(_e2, _e3); }                                  \
    pl32swap(W[0], W[2]); pl32swap(W[1], W[3]);                                   \
    pl32swap(W[4], W[6]); pl32swap(W[5], W[7]);                                   \
    { union { unsigned int u[4]; bf16x8 v; } _c0, _c1;                            \
      _c0.u[0] = W[0]; _c0.u[1] = W[1]; _c0.u[2] = W[2]; _c0.u[3] = W[3];         \
      _c1.u[0] = W[4]; _c1.u[1] = W[5]; _c1.u[2] = W[6]; _c1.u[3] = W[7];         \
      P0 = _c0.v; P1 = _c1.v; } }

#define ROUND(KC, VC, KN, VN, T, PRE) {                                           \
    if (PRE) { LOADK(KN, (T) + 1); LOADV(VN, (T) + 1); }                          \
    int k0 = (T) * 64;                                                            \
    f32x16 sc0, sc1;                                                              \
    _Pragma("unroll") for (int _r = 0; _r < 16; ++_r) { sc0[_r] = 0.f; sc1[_r] = 0.f; } \
    __builtin_amdgcn_s_setprio(1);                                                \
    _Pragma("unroll") for (int _j = 0; _j < 4; ++_j) {                            \
        sc0 = __builtin_amdgcn_mfma_f32_32x32x16_bf16(KC[_j],     qf[_j], sc0, 0, 0, 0); \
        sc1 = __builtin_amdgcn_mfma_f32_32x32x16_bf16(KC[4 + _j], qf[_j], sc1, 0, 0, 0); } \
    __builtin_amdgcn_s_setprio(0);                                                \
    if (k0 + 63 > qmin) {                                                         \
        int qglob = qmin + l31;                                                   \
        _Pragma("unroll") for (int _r = 0; _r < 16; ++_r) {                       \
            int krow = k0 + (_r & 3) + 8 * (_r >> 2) + 4 * hi;                    \
            if (krow > qglob)      sc0[_r] = -1e30f;                              \
            if (krow + 32 > qglob) sc1[_r] = -1e30f; } }                          \
    bf16x8 pf[4];                                                                 \
    SOFT(sc0, pf[0], pf[1]);                                                      \
    SOFT(sc1, pf[2], pf[3]);                                                      \
    __builtin_amdgcn_s_setprio(1);                                                \
    _Pragma("unroll") for (int _j = 0; _j < 4; ++_j) {                            \
        oo0 = __builtin_amdgcn_mfma_f32_32x32x16_bf16(pf[_j], VC[2 * _j],     oo0, 0, 0, 0); \
        oo1 = __builtin_amdgcn_mfma_f32_32x32x16_bf16(pf[_j], VC[2 * _j + 1], oo1, 0, 0, 0); } \
    __builtin_amdgcn_s_setprio(0); }

__global__ __launch_bounds__(64, 2) void attn_kernel(const ushort* __restrict__ Qg,
                                                     const ushort* __restrict__ Kp,
                                                     const ushort* __restrict__ Vp,
                                                     float* __restrict__ pO0,
                                                     float* __restrict__ pO1,
                                                     float* __restrict__ Rsum) {
    int lane = threadIdx.x;
    int l31  = lane & 31;
    int hi   = lane >> 5;
    int bh   = blockIdx.x;
    int y    = blockIdx.y;              // 0..31, long-first
    int w    = blockIdx.z;              // wave-of-four (q sub-block)
    int qt   = 15 - (y >> 1);
    int half = y & 1;
    int nt2  = qt + 1;                  // tiles per half-job
    int t_lo = half * nt2;
    int t_hi = t_lo + nt2;
    int q0   = qt * 128;
    int qmin = q0 + w * 32;
    // last tile this wave actually needs (rest fully masked)
    int tneed = ((qmin + 31) >> 6) + 1;
    int thw   = t_hi < tneed ? t_hi : tneed;

    size_t lane8 = (size_t)lane * 8;
    size_t Kbase = (size_t)bh * 131072;
    size_t Vbase = (size_t)bh * 131072;
    const ushort* Qb = Qg + (size_t)bh * S_DIM * HD_DIM;

    // Q fragments (B-operand: n=query=l31, k=hd = kk*16 + hi*8 + e)
    bf16x8 qf[4];
#pragma unroll
    for (int kk = 0; kk < 4; ++kk)
        qf[kk] = *(const bf16x8*)&Qb[(size_t)(qmin + l31) * HD_DIM + kk * 16 + hi * 8];

    f32x16 oo0, oo1;
#pragma unroll
    for (int r = 0; r < 16; ++r) { oo0[r] = 0.f; oo1[r] = 0.f; }
    float rsum = 0.f;

    bf16x8 kA[8], kB[8], vA[8], vB[8];
    int t = t_lo;
    if (t < thw) { LOADK(kA, t); LOADV(vA, t); }
    for (; t + 2 <= thw; t += 2) {
        ROUND(kA, vA, kB, vB, t, true);
        ROUND(kB, vB, kA, vA, t + 1, (t + 2 < thw));
    }
    if (t < thw) ROUND(kA, vA, kB, vB, t, false);

    // row sum across the two key-halves held by lanes l and l+32
    rsum += __shfl_xor(rsum, 32, 64);

    // epilogue: RAW partial O (f32) + partial rsum; combine kernel normalizes
    float* pO = half ? pO1 : pO0;
    int b = bh >> 4, h = bh & 15;
#pragma unroll
    for (int r = 0; r < 16; ++r) {
        int qrow = (r & 3) + 8 * (r >> 2) + 4 * hi;
        int q = qmin + qrow;
        size_t base = (size_t)(b * S_DIM + q) * D_DIM + h * HD_DIM;
        pO[base + l31]      = oo0[r];
        pO[base + 32 + l31] = oo1[r];
    }
    if (lane < 32)
        Rsum[half * (32 * S_DIM) + bh * S_DIM + qmin + lane] = rsum;
}

// ---------------------------------------------------------------------------
// Combine: attn = bf16((pO0 + pO1) / (r0 + r1)), elementwise over (B,S,D).
// One thread = 8 contiguous d within one head -> single rsum pair.
// ---------------------------------------------------------------------------
__global__ __launch_bounds__(256) void combine_kernel(const float* __restrict__ pO0,
                                                      const float* __restrict__ pO1,
                                                      const float* __restrict__ Rsum,
                                                      ushort* __restrict__ attn) {
    int e8 = blockIdx.x * 256 + threadIdx.x;      // 0..524287
    int d8 = e8 & 127;                            // D/8 index
    int s  = (e8 >> 7) & (S_DIM - 1);
    int b  = e8 >> 18;
    int bh = b * H_DIM + (d8 >> 3);
    float r0 = Rsum[bh * S_DIM + s];
    float r1 = Rsum[32 * S_DIM + bh * S_DIM + s];
    float inv = 1.f / (r0 + r1);
    size_t base = (size_t)e8 * 8;
    f32x4 a0 = *(const f32x4*)&pO0[base];
    f32x4 a1 = *(const f32x4*)&pO0[base + 4];
    f32x4 c0 = *(const f32x4*)&pO1[base];
    f32x4 c1 = *(const f32x4*)&pO1[base + 4];
    bf16x8 ov;
    ov[0] = f2bf((a0.x + c0.x) * inv); ov[1] = f2bf((a0.y + c0.y) * inv);
    ov[2] = f2bf((a0.z + c0.z) * inv); ov[3] = f2bf((a0.w + c0.w) * inv);
    ov[4] = f2bf((a1.x + c1.x) * inv); ov[5] = f2bf((a1.y + c1.y) * inv);
    ov[6] = f2bf((a1.z + c1.z) * inv); ov[7] = f2bf((a1.w + c1.w) * inv);
    *(bf16x8*)&attn[base] = ov;
}

// ---------------------------------------------------------------------------
extern "C" void kernel_launch(void* const* d_in, const int* in_sizes, int n_in,
                              void* d_out, int out_size, void* d_ws, size_t ws_size,
                              hipStream_t stream) {
    const void* x  = d_in[0];
    const void* Wq = d_in[1];
    const void* bq = d_in[2];
    const void* Wk = d_in[3];
    const void* bk = d_in[4];
    const void* Wv = d_in[5];
    const void* bv = d_in[6];
    const void* Wo = d_in[7];
    const void* bo = d_in[8];
    // d_in[9] = mask: exactly causal tril, handled analytically.

    char* ws = (char*)d_ws;
    const size_t MB = 1024 * 1024;
    const size_t base = 64 * 1024;
    int*    flag   = (int*)ws;
    float*  biasf  = (float*)(ws + 4096);
    ushort* xc     = (ushort*)(ws + base);                  // 8 MiB; reused as attn later
    ushort* Wqkvt  = (ushort*)(ws + base + 8  * MB);        // 6 MiB (3072x1024)
    ushort* Wot    = (ushort*)(ws + base + 14 * MB);        // 2 MiB
    ushort* Qc     = (ushort*)(ws + base + 16 * MB);        // 8 MiB Q (BH,S,64)
    ushort* Kpf    = (ushort*)(ws + base + 24 * MB);        // 8 MiB K fragment-packed
    ushort* Vpf    = (ushort*)(ws + base + 40 * MB);        // 8 MiB V fragment-packed
    float*  pO0    = (float*)(ws + base + 48 * MB);         // 16 MiB f32 partial
    float*  pO1    = (float*)(ws + base + 64 * MB);         // 16 MiB f32 partial
    float*  Rsum   = (float*)(ws + base + 80 * MB);         // 512 KiB (2x32x2048)
    ushort* attn   = xc;                                    // xc dead before combine writes

    dim3 tb(256);

    detect_kernel<<<1, tb, 0, stream>>>((const ushort*)x, flag);

    dim3 pg(16, 16, 6);
    prep_kernel<<<pg, tb, 0, stream>>>(x, Wq, Wk, Wv, Wo, bq, bk, bv, bo,
                                       xc, Wqkvt, Wot, biasf, flag);

    // Fused QKV projection: (4096x1024) x (3072x1024)^T
    dim3 gq(3 * D_DIM / 128, (B_DIM * S_DIM) / 128);   // (24, 32)
    gemm128_kernel<<<gq, tb, 0, stream>>>(xc, Wqkvt, biasf, Qc, Kpf, Vpf);

    dim3 ag(B_DIM * H_DIM, 32, 4);                     // 4096 one-wave jobs
    attn_kernel<<<ag, dim3(64), 0, stream>>>(Qc, Kpf, Vpf, pO0, pO1, Rsum);

    combine_kernel<<<2048, tb, 0, stream>>>(pO0, pO1, Rsum, attn);

    dim3 go(D_DIM / 128, (B_DIM * S_DIM) / 64);        // (8, 64) = 512 blocks
    gemm64_kernel<<<go, tb, 0, stream>>>(attn, Wot, biasf + 3072, d_out, flag);
}

// Round 6
// 187.388 us; speedup vs baseline: 1.0797x; 1.0445x over previous
//
#include <hip/hip_runtime.h>
#include <hip/hip_bf16.h>

typedef __attribute__((ext_vector_type(8))) short bf16x8;
typedef __attribute__((ext_vector_type(4))) float f32x4;
typedef __attribute__((ext_vector_type(16))) float f32x16;

#define B_DIM  2
#define S_DIM  2048
#define D_DIM  1024
#define H_DIM  16
#define HD_DIM 64

__device__ __forceinline__ float bf2f(ushort u) {
    union { unsigned int ui; float f; } c; c.ui = ((unsigned int)u) << 16; return c.f;
}
__device__ __forceinline__ ushort f2bf(float f) {
    __hip_bfloat16 h = __float2bfloat16(f);
    return *reinterpret_cast<ushort*>(&h);
}

// Async global->LDS DMA, 16 B per lane. LDS dest = wave-uniform base + lane*16.
__device__ __forceinline__ void async_cp16(const ushort* g, ushort* l) {
    __builtin_amdgcn_global_load_lds(
        (const __attribute__((address_space(1))) void*)g,
        (__attribute__((address_space(3))) void*)l, 16, 0, 0);
}

// pack two f32 -> one u32 of 2 bf16 (lo = first arg), RNE
__device__ __forceinline__ unsigned int cvt_pk_bf16(float lo, float hi) {
    unsigned int d;
    asm volatile("v_cvt_pk_bf16_f32 %0, %1, %2" : "=v"(d) : "v"(lo), "v"(hi));
    return d;
}
// after: a' = [a.lo32 | b.lo32], b' = [a.hi32 | b.hi32]
__device__ __forceinline__ void pl32swap(unsigned int& a, unsigned int& b) {
    asm volatile("v_permlane32_swap_b32 %0, %1" : "+v"(a), "+v"(b));
}

// ---------------------------------------------------------------------------
// Dtype detector: valid bf16 inputs never have exponent bits 0xFF; fp32 read
// as u16 halves hits 0xFF with p~1/256. flag=1 -> fp32 inputs, 0 -> bf16.
// ---------------------------------------------------------------------------
__global__ __launch_bounds__(256) void detect_kernel(const ushort* __restrict__ x,
                                                     int* __restrict__ flag) {
    __shared__ int any;
    int tid = threadIdx.x;
    if (tid == 0) any = 0;
    __syncthreads();
    int cnt = 0;
#pragma unroll
    for (int c = 0; c < 8; ++c) {
        bf16x8 v = *(const bf16x8*)&x[tid * 64 + c * 8];
#pragma unroll
        for (int e = 0; e < 8; ++e) {
            ushort u = (ushort)v[e];
            if (((u >> 7) & 0xFF) == 0xFF) cnt++;
        }
    }
    if (cnt) atomicOr(&any, 1);
    __syncthreads();
    if (tid == 0) *flag = any ? 1 : 0;
}

// ---------------------------------------------------------------------------
// Merged prep: grid (16,16,6).
//   z in 0..3 : convert + transpose weight z (Q/K/V -> Wqkvt slices, O -> Wot)
//   z == 4   : canonicalize x -> bf16 (4M elems) -- ONLY when input is f32
//              (bf16 inputs are consumed raw by gemm128; copy skipped)
//   z == 5   : biases -> fp32 (first 16 blocks)
// ---------------------------------------------------------------------------
__global__ __launch_bounds__(256) void prep_kernel(const void* __restrict__ x,
                                                   const void* __restrict__ Wq,
                                                   const void* __restrict__ Wk,
                                                   const void* __restrict__ Wv,
                                                   const void* __restrict__ Wo,
                                                   const void* __restrict__ bq,
                                                   const void* __restrict__ bk,
                                                   const void* __restrict__ bv,
                                                   const void* __restrict__ bo,
                                                   ushort* __restrict__ xc,
                                                   ushort* __restrict__ Wqkvt,
                                                   ushort* __restrict__ Wot,
                                                   float* __restrict__ biasf,
                                                   const int* __restrict__ flag) {
    int tid = threadIdx.x;
    int z = blockIdx.z;
    bool isf32 = (*flag != 0);

    if (z == 4) {
        if (!isf32) return;                               // raw bf16 x used directly
        int t = (blockIdx.y * 16 + blockIdx.x) * 256 + tid;   // 0..65535
#pragma unroll
        for (int c = 0; c < 8; ++c) {
            int i = t + c * 65536;                            // elem8 index
            const float* s = (const float*)x;
            f32x4 a = *(const f32x4*)&s[(size_t)i * 8];
            f32x4 b = *(const f32x4*)&s[(size_t)i * 8 + 4];
            bf16x8 o;
            o[0] = f2bf(a.x); o[1] = f2bf(a.y); o[2] = f2bf(a.z); o[3] = f2bf(a.w);
            o[4] = f2bf(b.x); o[5] = f2bf(b.y); o[6] = f2bf(b.z); o[7] = f2bf(b.w);
            *(bf16x8*)&xc[(size_t)i * 8] = o;
        }
        return;
    }
    if (z == 5) {
        int bid = blockIdx.y * 16 + blockIdx.x;
        if (bid >= 16) return;
        int i = bid * 256 + tid;                              // 0..4095
        int w = i >> 10, j = i & 1023;
        const void* s = (w == 0) ? bq : (w == 1) ? bk : (w == 2) ? bv : bo;
        biasf[i] = isf32 ? ((const float*)s)[j] : bf2f(((const ushort*)s)[j]);
        return;
    }

    // weight transpose
    __shared__ ushort tile[64][72];
    const void* src = (z == 0) ? Wq : (z == 1) ? Wk : (z == 2) ? Wv : Wo;
    ushort* dst = (z < 3) ? (Wqkvt + (size_t)z * D_DIM * D_DIM) : Wot;
    int r0 = blockIdx.y * 64, c0 = blockIdx.x * 64;
#pragma unroll
    for (int p = 0; p < 2; ++p) {
        int r = p * 32 + (tid >> 3);
        int c = (tid & 7) * 8;
        if (isf32) {
            const float* s = (const float*)src;
            f32x4 a = *(const f32x4*)&s[(size_t)(r0 + r) * D_DIM + c0 + c];
            f32x4 b = *(const f32x4*)&s[(size_t)(r0 + r) * D_DIM + c0 + c + 4];
            tile[r][c + 0] = f2bf(a.x); tile[r][c + 1] = f2bf(a.y);
            tile[r][c + 2] = f2bf(a.z); tile[r][c + 3] = f2bf(a.w);
            tile[r][c + 4] = f2bf(b.x); tile[r][c + 5] = f2bf(b.y);
            tile[r][c + 6] = f2bf(b.z); tile[r][c + 7] = f2bf(b.w);
        } else {
            *(bf16x8*)&tile[r][c] =
                *(const bf16x8*)&((const ushort*)src)[(size_t)(r0 + r) * D_DIM + c0 + c];
        }
    }
    __syncthreads();
#pragma unroll
    for (int p = 0; p < 2; ++p) {
        int n  = p * 32 + (tid >> 3);
        int cc = (tid & 7) * 8;
        bf16x8 v;
#pragma unroll
        for (int e = 0; e < 8; ++e) v[e] = (short)tile[cc + e][n];
        *(bf16x8*)&dst[(size_t)(c0 + n) * D_DIM + r0 + cc] = v;
    }
}

// ---------------------------------------------------------------------------
// Fused QKV GEMM: 128x128 tile, BK=64, global_load_lds(16B), XOR swizzle.
// A input selected device-side: raw x when bf16, converted xc when f32.
// Q -> (BH,S,64) bf16 (pre-scaled 0.125*log2e).
// K -> FRAGMENT-PACKED Kp[bh][t][mb][jm][hi][l31][e]: attn reads one coalesced
//      1KB dwordx4 per (mb,jm) fragment straight from L2, no LDS.
// V -> FRAGMENT-PACKED Vp[bh][t][j][nb][hi][l31][e] (uint2 stores preserved).
// ---------------------------------------------------------------------------
__global__ __launch_bounds__(256) void gemm128_kernel(const void* __restrict__ xraw,
                                                      const ushort* __restrict__ xc,
                                                      const ushort* __restrict__ Bt,
                                                      const float* __restrict__ bias,
                                                      ushort* __restrict__ qout,
                                                      ushort* __restrict__ kpout,
                                                      ushort* __restrict__ vpout,
                                                      const int* __restrict__ flag) {
    __shared__ ushort As[128 * 64];   // 16 KiB, unpadded
    __shared__ ushort Bs[128 * 64];
    const ushort* A = (*flag != 0) ? xc : (const ushort*)xraw;
    int tid  = threadIdx.x;
    int wave = tid >> 6;
    int lane = tid & 63;
    int l16  = lane & 15;
    int quad = lane >> 4;
    int m0   = blockIdx.y * 128;
    int n0   = blockIdx.x * 128;
    int wm   = wave >> 1;
    int wn   = wave & 1;
    const int K = 1024;

    f32x4 acc[4][4];
#pragma unroll
    for (int i = 0; i < 4; ++i)
#pragma unroll
        for (int j = 0; j < 4; ++j) acc[i][j] = (f32x4){0.f, 0.f, 0.f, 0.f};

    int lrow = lane >> 3;                         // 0..7 row within chunk
    int gcol = ((lane & 7) ^ lrow) * 8;           // swizzled column (elems)
    int sw   = l16 & 7;                           // fragment-read swizzle

    for (int kt = 0; kt < 16; ++kt) {
        int k0 = kt * 64;
#pragma unroll
        for (int j = 0; j < 4; ++j) {
            int chunk = wave * 4 + j;             // 0..15; 8 rows each
            int grow  = chunk * 8 + lrow;
            async_cp16(&A[(size_t)(m0 + grow) * K + k0 + gcol], &As[chunk * 512]);
            async_cp16(&Bt[(size_t)(n0 + grow) * K + k0 + gcol], &Bs[chunk * 512]);
        }
        __syncthreads();

#pragma unroll
        for (int kb = 0; kb < 2; ++kb) {
            bf16x8 af[4], bf[4];
#pragma unroll
            for (int i = 0; i < 4; ++i)
                af[i] = *(const bf16x8*)&As[(wm * 64 + i * 16 + l16) * 64 +
                                            (((kb * 4 + quad) ^ sw) << 3)];
#pragma unroll
            for (int j = 0; j < 4; ++j)
                bf[j] = *(const bf16x8*)&Bs[(wn * 64 + j * 16 + l16) * 64 +
                                            (((kb * 4 + quad) ^ sw) << 3)];
#pragma unroll
            for (int i = 0; i < 4; ++i)
#pragma unroll
                for (int j = 0; j < 4; ++j)
                    acc[i][j] = __builtin_amdgcn_mfma_f32_16x16x32_bf16(af[i], bf[j],
                                                                        acc[i][j], 0, 0, 0);
        }
        __syncthreads();
    }

#pragma unroll
    for (int j = 0; j < 4; ++j) {
        int n = n0 + wn * 64 + j * 16 + l16;        // C/D col = lane&15
        float bv = bias[n];
        int which = n >> 10;                        // 0=Q 1=K 2=V
        int n1 = n & 1023;
        int h = n1 >> 6, hd = n1 & 63;
#pragma unroll
        for (int i = 0; i < 4; ++i) {
            int mb = m0 + wm * 64 + i * 16 + quad * 4;     // row base (quad*4)
            int b = mb >> 11, s = mb & (S_DIM - 1);
            int bh = b * H_DIM + h;
            float v4[4];
#pragma unroll
            for (int r = 0; r < 4; ++r) v4[r] = acc[i][j][r] + bv;
            if (which == 2) {
                // V fragment-packed; s..s+3 contiguous e -> uint2 store
                ushort pk[4];
#pragma unroll
                for (int r = 0; r < 4; ++r) pk[r] = f2bf(v4[r]);
                size_t vidx = (size_t)bh * 131072 + (size_t)(s >> 6) * 4096 +
                              (size_t)((s >> 4) & 3) * 1024 + (size_t)(hd >> 5) * 512 +
                              (size_t)((s >> 3) & 1) * 256 + (size_t)(hd & 31) * 8 +
                              (s & 7);
                *(uint2*)&vpout[vidx] = *(uint2*)pk;
            } else if (which == 1) {
                // K fragment-packed; 4 scalar stores (stride 8 elems)
#pragma unroll
                for (int r = 0; r < 4; ++r) {
                    int key = s + r;
                    size_t kidx = (size_t)bh * 131072 + (size_t)(key >> 6) * 4096 +
                                  (size_t)((key >> 5) & 1) * 2048 +
                                  (size_t)(hd >> 4) * 512 +
                                  (size_t)((hd >> 3) & 1) * 256 +
                                  (size_t)(key & 31) * 8 + (hd & 7);
                    kpout[kidx] = f2bf(v4[r]);
                }
            } else {
#pragma unroll
                for (int r = 0; r < 4; ++r) {
                    // fold softmax scale AND log2(e) into Q (attn uses exp2)
                    float v = v4[r] * 0.18033688011f;      // 0.125 * log2(e)
                    qout[((((size_t)bh) * S_DIM + s + r) << 6) + hd] = f2bf(v);
                }
            }
        }
    }
}

// ---------------------------------------------------------------------------
// O-projection GEMM: 64x128 tile (M x N), BK=64, same staging/swizzle.
// ---------------------------------------------------------------------------
__global__ __launch_bounds__(256) void gemm64_kernel(const ushort* __restrict__ A,
                                                     const ushort* __restrict__ Bt,
                                                     const float* __restrict__ bias,
                                                     void* __restrict__ out,
                                                     const int* __restrict__ flag) {
    __shared__ ushort As[64 * 64];    // 8 KiB
    __shared__ ushort Bs[128 * 64];   // 16 KiB
    int tid  = threadIdx.x;
    int wave = tid >> 6;
    int lane = tid & 63;
    int l16  = lane & 15;
    int quad = lane >> 4;
    int m0   = blockIdx.y * 64;
    int n0   = blockIdx.x * 128;
    const int K = 1024;

    f32x4 acc[4][2];
#pragma unroll
    for (int i = 0; i < 4; ++i)
#pragma unroll
        for (int j = 0; j < 2; ++j) acc[i][j] = (f32x4){0.f, 0.f, 0.f, 0.f};

    int lrow = lane >> 3;
    int gcol = ((lane & 7) ^ lrow) * 8;
    int sw   = l16 & 7;

    for (int kt = 0; kt < 16; ++kt) {
        int k0 = kt * 64;
        // A: 8 chunks (2 per wave); B: 16 chunks (4 per wave)
#pragma unroll
        for (int j = 0; j < 2; ++j) {
            int chunk = wave * 2 + j;
            int grow  = chunk * 8 + lrow;
            async_cp16(&A[(size_t)(m0 + grow) * K + k0 + gcol], &As[chunk * 512]);
        }
#pragma unroll
        for (int j = 0; j < 4; ++j) {
            int chunk = wave * 4 + j;
            int grow  = chunk * 8 + lrow;
            async_cp16(&Bt[(size_t)(n0 + grow) * K + k0 + gcol], &Bs[chunk * 512]);
        }
        __syncthreads();

#pragma unroll
        for (int kb = 0; kb < 2; ++kb) {
            bf16x8 af[4], bf[2];
#pragma unroll
            for (int i = 0; i < 4; ++i)
                af[i] = *(const bf16x8*)&As[(i * 16 + l16) * 64 +
                                            (((kb * 4 + quad) ^ sw) << 3)];
#pragma unroll
            for (int j = 0; j < 2; ++j)
                bf[j] = *(const bf16x8*)&Bs[(wave * 32 + j * 16 + l16) * 64 +
                                            (((kb * 4 + quad) ^ sw) << 3)];
#pragma unroll
            for (int i = 0; i < 4; ++i)
#pragma unroll
                for (int j = 0; j < 2; ++j)
                    acc[i][j] = __builtin_amdgcn_mfma_f32_16x16x32_bf16(af[i], bf[j],
                                                                        acc[i][j], 0, 0, 0);
        }
        __syncthreads();
    }

    int outf32 = *flag;
#pragma unroll
    for (int j = 0; j < 2; ++j) {
        int n = n0 + wave * 32 + j * 16 + l16;
        float bv = bias[n];
#pragma unroll
        for (int i = 0; i < 4; ++i)
#pragma unroll
            for (int r = 0; r < 4; ++r) {
                int m = m0 + i * 16 + quad * 4 + r;
                float v = acc[i][j][r] + bv;
                if (outf32) ((float*)out)[(size_t)m * D_DIM + n] = v;
                else        ((ushort*)out)[(size_t)m * D_DIM + n] = f2bf(v);
            }
    }
}

// ---------------------------------------------------------------------------
// Causal attention v6: barrier-free, LDS-free per-wave streaming, NO SPLIT.
// v5's 1-wave de-phased structure removed the lockstep pathology that the
// v4 key-split was built for, so the split is pure overhead now (32MB f32
// partials + 40MB combine pass + 1 launch). Each wave owns its 32 queries'
// FULL key range, normalizes in-register, writes final bf16 directly.
// 2048 jobs (lengths 1..32 tiles), dispatched long-first; HW backfill keeps
// ~8 independent waves/CU. K/V read from L2 in fragment-packed layout
// (1KB coalesced dwordx4 per fragment), register double-buffered.
// ---------------------------------------------------------------------------
#define LOADK(DST, T) { size_t _b = Kbase + (size_t)(T) * 4096 + lane8;           \
    _Pragma("unroll") for (int _i = 0; _i < 8; ++_i)                              \
        DST[_i] = *(const bf16x8*)&Kp[_b + (size_t)((_i >> 2) * 2048 + (_i & 3) * 512)]; }

#define LOADV(DST, T) { size_t _b = Vbase + (size_t)(T) * 4096 + lane8;           \
    _Pragma("unroll") for (int _i = 0; _i < 8; ++_i)                              \
        DST[_i] = *(const bf16x8*)&Vp[_b + (size_t)((_i >> 1) * 1024 + (_i & 1) * 512)]; }

#define SOFT(SC, P0, P1) { unsigned int W[8];                                     \
    _Pragma("unroll") for (int _g = 0; _g < 4; ++_g) {                            \
        float _e0 = __builtin_amdgcn_exp2f(SC[4 * _g + 0]);                       \
        float _e1 = __builtin_amdgcn_exp2f(SC[4 * _g + 1]);                       \
        float _e2 = __builtin_amdgcn_exp2f(SC[4 * _g + 2]);                       \
        float _e3 = __builtin_amdgcn_exp2f(SC[4 * _g + 3]);                       \
        rsum += (_e0 + _e1) + (_e2 + _e3);                                        \
        W[2 * _g]     = cvt_pk_bf16(_e0, _e1);                                    \
        W[2 * _g + 1] = cvt_pk_bf16(_e2, _e3); }                                  \
    pl32swap(W[0], W[2]); pl32swap(W[1], W[3]);                                   \
    pl32swap(W[4], W[6]); pl32swap(W[5], W[7]);                                   \
    { union { unsigned int u[4]; bf16x8 v; } _c0, _c1;                            \
      _c0.u[0] = W[0]; _c0.u[1] = W[1]; _c0.u[2] = W[2]; _c0.u[3] = W[3];         \
      _c1.u[0] = W[4]; _c1.u[1] = W[5]; _c1.u[2] = W[6]; _c1.u[3] = W[7];         \
      P0 = _c0.v; P1 = _c1.v; } }

#define ROUND(KC, VC, KN, VN, T, PRE) {                                           \
    if (PRE) { LOADK(KN, (T) + 1); LOADV(VN, (T) + 1); }                          \
    int k0 = (T) * 64;                                                            \
    f32x16 sc0, sc1;                                                              \
    _Pragma("unroll") for (int _r = 0; _r < 16; ++_r) { sc0[_r] = 0.f; sc1[_r] = 0.f; } \
    __builtin_amdgcn_s_setprio(1);                                                \
    _Pragma("unroll") for (int _j = 0; _j < 4; ++_j) {                            \
        sc0 = __builtin_amdgcn_mfma_f32_32x32x16_bf16(KC[_j],     qf[_j], sc0, 0, 0, 0); \
        sc1 = __builtin_amdgcn_mfma_f32_32x32x16_bf16(KC[4 + _j], qf[_j], sc1, 0, 0, 0); } \
    __builtin_amdgcn_s_setprio(0);                                                \
    if (k0 + 63 > qmin) {                                                         \
        int qglob = qmin + l31;                                                   \
        _Pragma("unroll") for (int _r = 0; _r < 16; ++_r) {                       \
            int krow = k0 + (_r & 3) + 8 * (_r >> 2) + 4 * hi;                    \
            if (krow > qglob)      sc0[_r] = -1e30f;                              \
            if (krow + 32 > qglob) sc1[_r] = -1e30f; } }                          \
    bf16x8 pf[4];                                                                 \
    SOFT(sc0, pf[0], pf[1]);                                                      \
    SOFT(sc1, pf[2], pf[3]);                                                      \
    __builtin_amdgcn_s_setprio(1);                                                \
    _Pragma("unroll") for (int _j = 0; _j < 4; ++_j) {                            \
        oo0 = __builtin_amdgcn_mfma_f32_32x32x16_bf16(pf[_j], VC[2 * _j],     oo0, 0, 0, 0); \
        oo1 = __builtin_amdgcn_mfma_f32_32x32x16_bf16(pf[_j], VC[2 * _j + 1], oo1, 0, 0, 0); } \
    __builtin_amdgcn_s_setprio(0); }

__global__ __launch_bounds__(64, 2) void attn_kernel(const ushort* __restrict__ Qg,
                                                     const ushort* __restrict__ Kp,
                                                     const ushort* __restrict__ Vp,
                                                     ushort* __restrict__ attn_out) {
    int lane = threadIdx.x;
    int l31  = lane & 31;
    int hi   = lane >> 5;
    int idx  = blockIdx.x;              // 0..2047, long-first (qt descending)
    int qt   = 15 - (idx >> 7);
    int rr   = idx & 127;
    int bh   = rr >> 2;
    int w    = rr & 3;                  // 32-query sub-block within the q-tile
    int qmin = qt * 128 + w * 32;
    int thw  = ((qmin + 31) >> 6) + 1;  // tiles 0..thw-1 (rest fully masked)

    size_t lane8 = (size_t)lane * 8;
    size_t Kbase = (size_t)bh * 131072;
    size_t Vbase = (size_t)bh * 131072;
    const ushort* Qb = Qg + (size_t)bh * S_DIM * HD_DIM;

    // Q fragments (B-operand: n=query=l31, k=hd = kk*16 + hi*8 + e)
    bf16x8 qf[4];
#pragma unroll
    for (int kk = 0; kk < 4; ++kk)
        qf[kk] = *(const bf16x8*)&Qb[(size_t)(qmin + l31) * HD_DIM + kk * 16 + hi * 8];

    f32x16 oo0, oo1;
#pragma unroll
    for (int r = 0; r < 16; ++r) { oo0[r] = 0.f; oo1[r] = 0.f; }
    float rsum = 0.f;

    bf16x8 kA[8], kB[8], vA[8], vB[8];
    int t = 0;
    LOADK(kA, 0); LOADV(vA, 0);
    for (; t + 2 <= thw; t += 2) {
        ROUND(kA, vA, kB, vB, t, true);
        ROUND(kB, vB, kA, vA, t + 1, (t + 2 < thw));
    }
    if (t < thw) ROUND(kA, vA, kB, vB, t, false);

    // row sum across the two key-halves held by lanes l and l+32
    rsum += __shfl_xor(rsum, 32, 64);
    float inv = 1.f / rsum;             // lane q holds inv for query qmin+q (q<32)

    // epilogue: normalized bf16 write, C-frag row = (r&3)+8*(r>>2)+4*hi
    int b = bh >> 4, h = bh & 15;
#pragma unroll
    for (int r = 0; r < 16; ++r) {
        int qrow = (r & 3) + 8 * (r >> 2) + 4 * hi;
        float iv = __shfl(inv, qrow, 64);
        int q = qmin + qrow;
        size_t base = (size_t)(b * S_DIM + q) * D_DIM + h * HD_DIM;
        attn_out[base + l31]      = f2bf(oo0[r] * iv);
        attn_out[base + 32 + l31] = f2bf(oo1[r] * iv);
    }
}

// ---------------------------------------------------------------------------
extern "C" void kernel_launch(void* const* d_in, const int* in_sizes, int n_in,
                              void* d_out, int out_size, void* d_ws, size_t ws_size,
                              hipStream_t stream) {
    const void* x  = d_in[0];
    const void* Wq = d_in[1];
    const void* bq = d_in[2];
    const void* Wk = d_in[3];
    const void* bk = d_in[4];
    const void* Wv = d_in[5];
    const void* bv = d_in[6];
    const void* Wo = d_in[7];
    const void* bo = d_in[8];
    // d_in[9] = mask: exactly causal tril, handled analytically.

    char* ws = (char*)d_ws;
    const size_t MB = 1024 * 1024;
    const size_t base = 64 * 1024;
    int*    flag   = (int*)ws;
    float*  biasf  = (float*)(ws + 4096);
    ushort* xc     = (ushort*)(ws + base);                  // 8 MiB; reused as attn later
    ushort* Wqkvt  = (ushort*)(ws + base + 8  * MB);        // 6 MiB (3072x1024)
    ushort* Wot    = (ushort*)(ws + base + 14 * MB);        // 2 MiB
    ushort* Qc     = (ushort*)(ws + base + 16 * MB);        // 8 MiB Q (BH,S,64)
    ushort* Kpf    = (ushort*)(ws + base + 24 * MB);        // 8 MiB K fragment-packed
    ushort* Vpf    = (ushort*)(ws + base + 40 * MB);        // 8 MiB V fragment-packed
    ushort* attn   = xc;                                    // xc dead before attn writes

    dim3 tb(256);

    detect_kernel<<<1, tb, 0, stream>>>((const ushort*)x, flag);

    dim3 pg(16, 16, 6);
    prep_kernel<<<pg, tb, 0, stream>>>(x, Wq, Wk, Wv, Wo, bq, bk, bv, bo,
                                       xc, Wqkvt, Wot, biasf, flag);

    // Fused QKV projection: (4096x1024) x (3072x1024)^T
    dim3 gq(3 * D_DIM / 128, (B_DIM * S_DIM) / 128);   // (24, 32)
    gemm128_kernel<<<gq, tb, 0, stream>>>(x, xc, Wqkvt, biasf, Qc, Kpf, Vpf, flag);

    attn_kernel<<<2048, dim3(64), 0, stream>>>(Qc, Kpf, Vpf, attn);

    dim3 go(D_DIM / 128, (B_DIM * S_DIM) / 64);        // (8, 64) = 512 blocks
    gemm64_kernel<<<go, tb, 0, stream>>>(attn, Wot, biasf + 3072, d_out, flag);
}

// Round 7
// 184.380 us; speedup vs baseline: 1.0973x; 1.0163x over previous
//
#include <hip/hip_runtime.h>
#include <hip/hip_bf16.h>

typedef __attribute__((ext_vector_type(8))) short bf16x8;
typedef __attribute__((ext_vector_type(4))) float f32x4;
typedef __attribute__((ext_vector_type(16))) float f32x16;

#define B_DIM  2
#define S_DIM  2048
#define D_DIM  1024
#define H_DIM  16
#define HD_DIM 64

__device__ __forceinline__ float bf2f(ushort u) {
    union { unsigned int ui; float f; } c; c.ui = ((unsigned int)u) << 16; return c.f;
}
__device__ __forceinline__ ushort f2bf(float f) {
    __hip_bfloat16 h = __float2bfloat16(f);
    return *reinterpret_cast<ushort*>(&h);
}

// Async global->LDS DMA, 16 B per lane. LDS dest = wave-uniform base + lane*16.
__device__ __forceinline__ void async_cp16(const ushort* g, ushort* l) {
    __builtin_amdgcn_global_load_lds(
        (const __attribute__((address_space(1))) void*)g,
        (__attribute__((address_space(3))) void*)l, 16, 0, 0);
}

// pack two f32 -> one u32 of 2 bf16 (lo = first arg), RNE
__device__ __forceinline__ unsigned int cvt_pk_bf16(float lo, float hi) {
    unsigned int d;
    asm volatile("v_cvt_pk_bf16_f32 %0, %1, %2" : "=v"(d) : "v"(lo), "v"(hi));
    return d;
}
// after: a' = [a.lo32 | b.lo32], b' = [a.hi32 | b.hi32]
__device__ __forceinline__ void pl32swap(unsigned int& a, unsigned int& b) {
    asm volatile("v_permlane32_swap_b32 %0, %1" : "+v"(a), "+v"(b));
}

// ---------------------------------------------------------------------------
// Dtype detector: valid bf16 inputs never have exponent bits 0xFF; fp32 read
// as u16 halves hits 0xFF with p~1/256. flag=1 -> fp32 inputs, 0 -> bf16.
// ---------------------------------------------------------------------------
__global__ __launch_bounds__(256) void detect_kernel(const ushort* __restrict__ x,
                                                     int* __restrict__ flag) {
    __shared__ int any;
    int tid = threadIdx.x;
    if (tid == 0) any = 0;
    __syncthreads();
    int cnt = 0;
#pragma unroll
    for (int c = 0; c < 8; ++c) {
        bf16x8 v = *(const bf16x8*)&x[tid * 64 + c * 8];
#pragma unroll
        for (int e = 0; e < 8; ++e) {
            ushort u = (ushort)v[e];
            if (((u >> 7) & 0xFF) == 0xFF) cnt++;
        }
    }
    if (cnt) atomicOr(&any, 1);
    __syncthreads();
    if (tid == 0) *flag = any ? 1 : 0;
}

// ---------------------------------------------------------------------------
// Merged prep: grid (16,16,6).
//   z in 0..3 : convert + transpose weight z (Q/K/V -> Wqkvt slices, O -> Wot)
//   z == 4   : canonicalize x -> bf16 (4M elems) -- ONLY when input is f32
//              (bf16 inputs are consumed raw by gemm128; copy skipped)
//   z == 5   : biases -> fp32 (first 16 blocks)
// ---------------------------------------------------------------------------
__global__ __launch_bounds__(256) void prep_kernel(const void* __restrict__ x,
                                                   const void* __restrict__ Wq,
                                                   const void* __restrict__ Wk,
                                                   const void* __restrict__ Wv,
                                                   const void* __restrict__ Wo,
                                                   const void* __restrict__ bq,
                                                   const void* __restrict__ bk,
                                                   const void* __restrict__ bv,
                                                   const void* __restrict__ bo,
                                                   ushort* __restrict__ xc,
                                                   ushort* __restrict__ Wqkvt,
                                                   ushort* __restrict__ Wot,
                                                   float* __restrict__ biasf,
                                                   const int* __restrict__ flag) {
    int tid = threadIdx.x;
    int z = blockIdx.z;
    bool isf32 = (*flag != 0);

    if (z == 4) {
        if (!isf32) return;                               // raw bf16 x used directly
        int t = (blockIdx.y * 16 + blockIdx.x) * 256 + tid;   // 0..65535
#pragma unroll
        for (int c = 0; c < 8; ++c) {
            int i = t + c * 65536;                            // elem8 index
            const float* s = (const float*)x;
            f32x4 a = *(const f32x4*)&s[(size_t)i * 8];
            f32x4 b = *(const f32x4*)&s[(size_t)i * 8 + 4];
            bf16x8 o;
            o[0] = f2bf(a.x); o[1] = f2bf(a.y); o[2] = f2bf(a.z); o[3] = f2bf(a.w);
            o[4] = f2bf(b.x); o[5] = f2bf(b.y); o[6] = f2bf(b.z); o[7] = f2bf(b.w);
            *(bf16x8*)&xc[(size_t)i * 8] = o;
        }
        return;
    }
    if (z == 5) {
        int bid = blockIdx.y * 16 + blockIdx.x;
        if (bid >= 16) return;
        int i = bid * 256 + tid;                              // 0..4095
        int w = i >> 10, j = i & 1023;
        const void* s = (w == 0) ? bq : (w == 1) ? bk : (w == 2) ? bv : bo;
        biasf[i] = isf32 ? ((const float*)s)[j] : bf2f(((const ushort*)s)[j]);
        return;
    }

    // weight transpose
    __shared__ ushort tile[64][72];
    const void* src = (z == 0) ? Wq : (z == 1) ? Wk : (z == 2) ? Wv : Wo;
    ushort* dst = (z < 3) ? (Wqkvt + (size_t)z * D_DIM * D_DIM) : Wot;
    int r0 = blockIdx.y * 64, c0 = blockIdx.x * 64;
#pragma unroll
    for (int p = 0; p < 2; ++p) {
        int r = p * 32 + (tid >> 3);
        int c = (tid & 7) * 8;
        if (isf32) {
            const float* s = (const float*)src;
            f32x4 a = *(const f32x4*)&s[(size_t)(r0 + r) * D_DIM + c0 + c];
            f32x4 b = *(const f32x4*)&s[(size_t)(r0 + r) * D_DIM + c0 + c + 4];
            tile[r][c + 0] = f2bf(a.x); tile[r][c + 1] = f2bf(a.y);
            tile[r][c + 2] = f2bf(a.z); tile[r][c + 3] = f2bf(a.w);
            tile[r][c + 4] = f2bf(b.x); tile[r][c + 5] = f2bf(b.y);
            tile[r][c + 6] = f2bf(b.z); tile[r][c + 7] = f2bf(b.w);
        } else {
            *(bf16x8*)&tile[r][c] =
                *(const bf16x8*)&((const ushort*)src)[(size_t)(r0 + r) * D_DIM + c0 + c];
        }
    }
    __syncthreads();
#pragma unroll
    for (int p = 0; p < 2; ++p) {
        int n  = p * 32 + (tid >> 3);
        int cc = (tid & 7) * 8;
        bf16x8 v;
#pragma unroll
        for (int e = 0; e < 8; ++e) v[e] = (short)tile[cc + e][n];
        *(bf16x8*)&dst[(size_t)(c0 + n) * D_DIM + r0 + cc] = v;
    }
}

// ---------------------------------------------------------------------------
// Fused QKV GEMM: 128x128 tile, BK=64, global_load_lds(16B), XOR swizzle.
// A input selected device-side: raw x when bf16, converted xc when f32.
// Q -> (BH,S,64) bf16 (pre-scaled 0.125*log2e).
// K -> FRAGMENT-PACKED Kp[bh][t][mb][jm][hi][l31][e]: attn reads one coalesced
//      1KB dwordx4 per (mb,jm) fragment straight from L2, no LDS.
// V -> FRAGMENT-PACKED Vp[bh][t][j][nb][hi][l31][e] (uint2 stores preserved).
// ---------------------------------------------------------------------------
__global__ __launch_bounds__(256) void gemm128_kernel(const void* __restrict__ xraw,
                                                      const ushort* __restrict__ xc,
                                                      const ushort* __restrict__ Bt,
                                                      const float* __restrict__ bias,
                                                      ushort* __restrict__ qout,
                                                      ushort* __restrict__ kpout,
                                                      ushort* __restrict__ vpout,
                                                      const int* __restrict__ flag) {
    __shared__ ushort As[128 * 64];   // 16 KiB, unpadded
    __shared__ ushort Bs[128 * 64];
    const ushort* A = (*flag != 0) ? xc : (const ushort*)xraw;
    int tid  = threadIdx.x;
    int wave = tid >> 6;
    int lane = tid & 63;
    int l16  = lane & 15;
    int quad = lane >> 4;
    int m0   = blockIdx.y * 128;
    int n0   = blockIdx.x * 128;
    int wm   = wave >> 1;
    int wn   = wave & 1;
    const int K = 1024;

    f32x4 acc[4][4];
#pragma unroll
    for (int i = 0; i < 4; ++i)
#pragma unroll
        for (int j = 0; j < 4; ++j) acc[i][j] = (f32x4){0.f, 0.f, 0.f, 0.f};

    int lrow = lane >> 3;                         // 0..7 row within chunk
    int gcol = ((lane & 7) ^ lrow) * 8;           // swizzled column (elems)
    int sw   = l16 & 7;                           // fragment-read swizzle

    for (int kt = 0; kt < 16; ++kt) {
        int k0 = kt * 64;
#pragma unroll
        for (int j = 0; j < 4; ++j) {
            int chunk = wave * 4 + j;             // 0..15; 8 rows each
            int grow  = chunk * 8 + lrow;
            async_cp16(&A[(size_t)(m0 + grow) * K + k0 + gcol], &As[chunk * 512]);
            async_cp16(&Bt[(size_t)(n0 + grow) * K + k0 + gcol], &Bs[chunk * 512]);
        }
        __syncthreads();

#pragma unroll
        for (int kb = 0; kb < 2; ++kb) {
            bf16x8 af[4], bf[4];
#pragma unroll
            for (int i = 0; i < 4; ++i)
                af[i] = *(const bf16x8*)&As[(wm * 64 + i * 16 + l16) * 64 +
                                            (((kb * 4 + quad) ^ sw) << 3)];
#pragma unroll
            for (int j = 0; j < 4; ++j)
                bf[j] = *(const bf16x8*)&Bs[(wn * 64 + j * 16 + l16) * 64 +
                                            (((kb * 4 + quad) ^ sw) << 3)];
#pragma unroll
            for (int i = 0; i < 4; ++i)
#pragma unroll
                for (int j = 0; j < 4; ++j)
                    acc[i][j] = __builtin_amdgcn_mfma_f32_16x16x32_bf16(af[i], bf[j],
                                                                        acc[i][j], 0, 0, 0);
        }
        __syncthreads();
    }

#pragma unroll
    for (int j = 0; j < 4; ++j) {
        int n = n0 + wn * 64 + j * 16 + l16;        // C/D col = lane&15
        float bv = bias[n];
        int which = n >> 10;                        // 0=Q 1=K 2=V
        int n1 = n & 1023;
        int h = n1 >> 6, hd = n1 & 63;
#pragma unroll
        for (int i = 0; i < 4; ++i) {
            int mb = m0 + wm * 64 + i * 16 + quad * 4;     // row base (quad*4)
            int b = mb >> 11, s = mb & (S_DIM - 1);
            int bh = b * H_DIM + h;
            float v4[4];
#pragma unroll
            for (int r = 0; r < 4; ++r) v4[r] = acc[i][j][r] + bv;
            if (which == 2) {
                // V fragment-packed; s..s+3 contiguous e -> uint2 store
                ushort pk[4];
#pragma unroll
                for (int r = 0; r < 4; ++r) pk[r] = f2bf(v4[r]);
                size_t vidx = (size_t)bh * 131072 + (size_t)(s >> 6) * 4096 +
                              (size_t)((s >> 4) & 3) * 1024 + (size_t)(hd >> 5) * 512 +
                              (size_t)((s >> 3) & 1) * 256 + (size_t)(hd & 31) * 8 +
                              (s & 7);
                *(uint2*)&vpout[vidx] = *(uint2*)pk;
            } else if (which == 1) {
                // K fragment-packed; 4 scalar stores (stride 8 elems)
#pragma unroll
                for (int r = 0; r < 4; ++r) {
                    int key = s + r;
                    size_t kidx = (size_t)bh * 131072 + (size_t)(key >> 6) * 4096 +
                                  (size_t)((key >> 5) & 1) * 2048 +
                                  (size_t)(hd >> 4) * 512 +
                                  (size_t)((hd >> 3) & 1) * 256 +
                                  (size_t)(key & 31) * 8 + (hd & 7);
                    kpout[kidx] = f2bf(v4[r]);
                }
            } else {
#pragma unroll
                for (int r = 0; r < 4; ++r) {
                    // fold softmax scale AND log2(e) into Q (attn uses exp2)
                    float v = v4[r] * 0.18033688011f;      // 0.125 * log2(e)
                    qout[((((size_t)bh) * S_DIM + s + r) << 6) + hd] = f2bf(v);
                }
            }
        }
    }
}

// ---------------------------------------------------------------------------
// O-projection GEMM: 64x128 tile (M x N), BK=64, same staging/swizzle.
// ---------------------------------------------------------------------------
__global__ __launch_bounds__(256) void gemm64_kernel(const ushort* __restrict__ A,
                                                     const ushort* __restrict__ Bt,
                                                     const float* __restrict__ bias,
                                                     void* __restrict__ out,
                                                     const int* __restrict__ flag) {
    __shared__ ushort As[64 * 64];    // 8 KiB
    __shared__ ushort Bs[128 * 64];   // 16 KiB
    int tid  = threadIdx.x;
    int wave = tid >> 6;
    int lane = tid & 63;
    int l16  = lane & 15;
    int quad = lane >> 4;
    int m0   = blockIdx.y * 64;
    int n0   = blockIdx.x * 128;
    const int K = 1024;

    f32x4 acc[4][2];
#pragma unroll
    for (int i = 0; i < 4; ++i)
#pragma unroll
        for (int j = 0; j < 2; ++j) acc[i][j] = (f32x4){0.f, 0.f, 0.f, 0.f};

    int lrow = lane >> 3;
    int gcol = ((lane & 7) ^ lrow) * 8;
    int sw   = l16 & 7;

    for (int kt = 0; kt < 16; ++kt) {
        int k0 = kt * 64;
        // A: 8 chunks (2 per wave); B: 16 chunks (4 per wave)
#pragma unroll
        for (int j = 0; j < 2; ++j) {
            int chunk = wave * 2 + j;
            int grow  = chunk * 8 + lrow;
            async_cp16(&A[(size_t)(m0 + grow) * K + k0 + gcol], &As[chunk * 512]);
        }
#pragma unroll
        for (int j = 0; j < 4; ++j) {
            int chunk = wave * 4 + j;
            int grow  = chunk * 8 + lrow;
            async_cp16(&Bt[(size_t)(n0 + grow) * K + k0 + gcol], &Bs[chunk * 512]);
        }
        __syncthreads();

#pragma unroll
        for (int kb = 0; kb < 2; ++kb) {
            bf16x8 af[4], bf[2];
#pragma unroll
            for (int i = 0; i < 4; ++i)
                af[i] = *(const bf16x8*)&As[(i * 16 + l16) * 64 +
                                            (((kb * 4 + quad) ^ sw) << 3)];
#pragma unroll
            for (int j = 0; j < 2; ++j)
                bf[j] = *(const bf16x8*)&Bs[(wave * 32 + j * 16 + l16) * 64 +
                                            (((kb * 4 + quad) ^ sw) << 3)];
#pragma unroll
            for (int i = 0; i < 4; ++i)
#pragma unroll
                for (int j = 0; j < 2; ++j)
                    acc[i][j] = __builtin_amdgcn_mfma_f32_16x16x32_bf16(af[i], bf[j],
                                                                        acc[i][j], 0, 0, 0);
        }
        __syncthreads();
    }

    int outf32 = *flag;
#pragma unroll
    for (int j = 0; j < 2; ++j) {
        int n = n0 + wave * 32 + j * 16 + l16;
        float bv = bias[n];
#pragma unroll
        for (int i = 0; i < 4; ++i)
#pragma unroll
            for (int r = 0; r < 4; ++r) {
                int m = m0 + i * 16 + quad * 4 + r;
                float v = acc[i][j][r] + bv;
                if (outf32) ((float*)out)[(size_t)m * D_DIM + n] = v;
                else        ((ushort*)out)[(size_t)m * D_DIM + n] = f2bf(v);
            }
    }
}

// ---------------------------------------------------------------------------
// Causal attention v7: v6 + XCD-locality swizzle.
// v6 analysis: K/V re-read volume is 33792 wave-tiles x 16KB = 540 MB/dispatch.
// One bh's K+V = 512 KB, but its 64 jobs scattered over all 8 XCDs -> each
// XCD touches ~16 MB >> its 4 MiB L2 -> reads served by Infinity Cache
// (~35 us observed; L2 floor would be ~16 us). Fix: pin all jobs of bh to
// XCD bh&7 via blockIdx = xcd + 8*rank (dispatch round-robins bid%8 -> XCD).
// Each XCD then streams 4 bh x 512 KB = 2 MB of K/V, L2-resident.
// Per-XCD rank order: qt descending (long-first) -> even backfill over the
// XCD's 32 CUs (jobs are 1..32 tiles long). Everything else unchanged:
// barrier-free 1-wave jobs, fragment-packed K/V, reg double-buffer,
// in-register softmax+transpose, direct normalized bf16 write.
// ---------------------------------------------------------------------------
#define LOADK(DST, T) { size_t _b = Kbase + (size_t)(T) * 4096 + lane8;           \
    _Pragma("unroll") for (int _i = 0; _i < 8; ++_i)                              \
        DST[_i] = *(const bf16x8*)&Kp[_b + (size_t)((_i >> 2) * 2048 + (_i & 3) * 512)]; }

#define LOADV(DST, T) { size_t _b = Vbase + (size_t)(T) * 4096 + lane8;           \
    _Pragma("unroll") for (int _i = 0; _i < 8; ++_i)                              \
        DST[_i] = *(const bf16x8*)&Vp[_b + (size_t)((_i >> 1) * 1024 + (_i & 1) * 512)]; }

#define SOFT(SC, P0, P1) { unsigned int W[8];                                     \
    _Pragma("unroll") for (int _g = 0; _g < 4; ++_g) {                            \
        float _e0 = __builtin_amdgcn_exp2f(SC[4 * _g + 0]);                       \
        float _e1 = __builtin_amdgcn_exp2f(SC[4 * _g + 1]);                       \
        float _e2 = __builtin_amdgcn_exp2f(SC[4 * _g + 2]);                       \
        float _e3 = __builtin_amdgcn_exp2f(SC[4 * _g + 3]);                       \
        rsum += (_e0 + _e1) + (_e2 + _e3);                                        \
        W[2 * _g]     = cvt_pk_bf16(_e0, _e1);                                    \
        W[2 * _g + 1] = cvt_pk_bf16(_e2, _e3); }                                  \
    pl32swap(W[0], W[2]); pl32swap(W[1], W[3]);                                   \
    pl32swap(W[4], W[6]); pl32swap(W[5], W[7]);                                   \
    { union { unsigned int u[4]; bf16x8 v; } _c0, _c1;                            \
      _c0.u[0] = W[0]; _c0.u[1] = W[1]; _c0.u[2] = W[2]; _c0.u[3] = W[3];         \
      _c1.u[0] = W[4]; _c1.u[1] = W[5]; _c1.u[2] = W[6]; _c1.u[3] = W[7];         \
      P0 = _c0.v; P1 = _c1.v; } }

#define ROUND(KC, VC, KN, VN, T, PRE) {                                           \
    if (PRE) { LOADK(KN, (T) + 1); LOADV(VN, (T) + 1); }                          \
    int k0 = (T) * 64;                                                            \
    f32x16 sc0, sc1;                                                              \
    _Pragma("unroll") for (int _r = 0; _r < 16; ++_r) { sc0[_r] = 0.f; sc1[_r] = 0.f; } \
    __builtin_amdgcn_s_setprio(1);                                                \
    _Pragma("unroll") for (int _j = 0; _j < 4; ++_j) {                            \
        sc0 = __builtin_amdgcn_mfma_f32_32x32x16_bf16(KC[_j],     qf[_j], sc0, 0, 0, 0); \
        sc1 = __builtin_amdgcn_mfma_f32_32x32x16_bf16(KC[4 + _j], qf[_j], sc1, 0, 0, 0); } \
    __builtin_amdgcn_s_setprio(0);                                                \
    if (k0 + 63 > qmin) {                                                         \
        int qglob = qmin + l31;                                                   \
        _Pragma("unroll") for (int _r = 0; _r < 16; ++_r) {                       \
            int krow = k0 + (_r & 3) + 8 * (_r >> 2) + 4 * hi;                    \
            if (krow > qglob)      sc0[_r] = -1e30f;                              \
            if (krow + 32 > qglob) sc1[_r] = -1e30f; } }                          \
    bf16x8 pf[4];                                                                 \
    SOFT(sc0, pf[0], pf[1]);                                                      \
    SOFT(sc1, pf[2], pf[3]);                                                      \
    __builtin_amdgcn_s_setprio(1);                                                \
    _Pragma("unroll") for (int _j = 0; _j < 4; ++_j) {                            \
        oo0 = __builtin_amdgcn_mfma_f32_32x32x16_bf16(pf[_j], VC[2 * _j],     oo0, 0, 0, 0); \
        oo1 = __builtin_amdgcn_mfma_f32_32x32x16_bf16(pf[_j], VC[2 * _j + 1], oo1, 0, 0, 0); } \
    __builtin_amdgcn_s_setprio(0); }

__global__ __launch_bounds__(64, 2) void attn_kernel(const ushort* __restrict__ Qg,
                                                     const ushort* __restrict__ Kp,
                                                     const ushort* __restrict__ Vp,
                                                     ushort* __restrict__ attn_out) {
    int lane = threadIdx.x;
    int l31  = lane & 31;
    int hi   = lane >> 5;
    // XCD-locality decode: bid = xcd + 8*rank; rank = qt-desc | bh-group | w.
    int bid  = blockIdx.x;              // 0..2047
    int xcd  = bid & 7;                 // presumed XCD (round-robin bid%8)
    int rank = bid >> 3;                // 0..255 within XCD
    int qt   = 15 - (rank >> 4);        // long-first within the XCD
    int rem  = rank & 15;
    int bh   = xcd + 8 * (rem >> 2);    // bh & 7 == xcd  (4 bh per XCD)
    int w    = rem & 3;                 // 32-query sub-block within the q-tile
    int qmin = qt * 128 + w * 32;
    int thw  = ((qmin + 31) >> 6) + 1;  // tiles 0..thw-1 (rest fully masked)

    size_t lane8 = (size_t)lane * 8;
    size_t Kbase = (size_t)bh * 131072;
    size_t Vbase = (size_t)bh * 131072;
    const ushort* Qb = Qg + (size_t)bh * S_DIM * HD_DIM;

    // Q fragments (B-operand: n=query=l31, k=hd = kk*16 + hi*8 + e)
    bf16x8 qf[4];
#pragma unroll
    for (int kk = 0; kk < 4; ++kk)
        qf[kk] = *(const bf16x8*)&Qb[(size_t)(qmin + l31) * HD_DIM + kk * 16 + hi * 8];

    f32x16 oo0, oo1;
#pragma unroll
    for (int r = 0; r < 16; ++r) { oo0[r] = 0.f; oo1[r] = 0.f; }
    float rsum = 0.f;

    bf16x8 kA[8], kB[8], vA[8], vB[8];
    int t = 0;
    LOADK(kA, 0); LOADV(vA, 0);
    for (; t + 2 <= thw; t += 2) {
        ROUND(kA, vA, kB, vB, t, true);
        ROUND(kB, vB, kA, vA, t + 1, (t + 2 < thw));
    }
    if (t < thw) ROUND(kA, vA, kB, vB, t, false);

    // row sum across the two key-halves held by lanes l and l+32
    rsum += __shfl_xor(rsum, 32, 64);
    float inv = 1.f / rsum;             // lane q holds inv for query qmin+q (q<32)

    // epilogue: normalized bf16 write, C-frag row = (r&3)+8*(r>>2)+4*hi
    int b = bh >> 4, h = bh & 15;
#pragma unroll
    for (int r = 0; r < 16; ++r) {
        int qrow = (r & 3) + 8 * (r >> 2) + 4 * hi;
        float iv = __shfl(inv, qrow, 64);
        int q = qmin + qrow;
        size_t base = (size_t)(b * S_DIM + q) * D_DIM + h * HD_DIM;
        attn_out[base + l31]      = f2bf(oo0[r] * iv);
        attn_out[base + 32 + l31] = f2bf(oo1[r] * iv);
    }
}

// ---------------------------------------------------------------------------
extern "C" void kernel_launch(void* const* d_in, const int* in_sizes, int n_in,
                              void* d_out, int out_size, void* d_ws, size_t ws_size,
                              hipStream_t stream) {
    const void* x  = d_in[0];
    const void* Wq = d_in[1];
    const void* bq = d_in[2];
    const void* Wk = d_in[3];
    const void* bk = d_in[4];
    const void* Wv = d_in[5];
    const void* bv = d_in[6];
    const void* Wo = d_in[7];
    const void* bo = d_in[8];
    // d_in[9] = mask: exactly causal tril, handled analytically.

    char* ws = (char*)d_ws;
    const size_t MB = 1024 * 1024;
    const size_t base = 64 * 1024;
    int*    flag   = (int*)ws;
    float*  biasf  = (float*)(ws + 4096);
    ushort* xc     = (ushort*)(ws + base);                  // 8 MiB; reused as attn later
    ushort* Wqkvt  = (ushort*)(ws + base + 8  * MB);        // 6 MiB (3072x1024)
    ushort* Wot    = (ushort*)(ws + base + 14 * MB);        // 2 MiB
    ushort* Qc     = (ushort*)(ws + base + 16 * MB);        // 8 MiB Q (BH,S,64)
    ushort* Kpf    = (ushort*)(ws + base + 24 * MB);        // 8 MiB K fragment-packed
    ushort* Vpf    = (ushort*)(ws + base + 40 * MB);        // 8 MiB V fragment-packed
    ushort* attn   = xc;                                    // xc dead before attn writes

    dim3 tb(256);

    detect_kernel<<<1, tb, 0, stream>>>((const ushort*)x, flag);

    dim3 pg(16, 16, 6);
    prep_kernel<<<pg, tb, 0, stream>>>(x, Wq, Wk, Wv, Wo, bq, bk, bv, bo,
                                       xc, Wqkvt, Wot, biasf, flag);

    // Fused QKV projection: (4096x1024) x (3072x1024)^T
    dim3 gq(3 * D_DIM / 128, (B_DIM * S_DIM) / 128);   // (24, 32)
    gemm128_kernel<<<gq, tb, 0, stream>>>(x, xc, Wqkvt, biasf, Qc, Kpf, Vpf, flag);

    attn_kernel<<<2048, dim3(64), 0, stream>>>(Qc, Kpf, Vpf, attn);

    dim3 go(D_DIM / 128, (B_DIM * S_DIM) / 64);        // (8, 64) = 512 blocks
    gemm64_kernel<<<go, tb, 0, stream>>>(attn, Wot, biasf + 3072, d_out, flag);
}